// Round 19
// baseline (642.101 us; speedup 1.0000x reference)
//
#include <hip/hip_runtime.h>
#include <hip/hip_fp16.h>
#include <math.h>

#define NE 150000

// type ids: SB=0 PQ=1 PV=2 NB=3
__constant__ int c_stype[15] = {2,0,0,2,3,1,0,1,3,1,2,3,2,1,3};
__constant__ int c_dtype[15] = {0,1,3,1,1,3,2,0,0,2,3,2,2,1,3};
__constant__ int c_slot[15]  = {0,0,0,1,2,1,0,1,2,1,2,2,3,3,3};
__constant__ int c_N[4]      = {4000,30000,15000,12000};
__constant__ int c_xoff[4]   = {0,4000,34000,49000};
__constant__ int c_cnt[4]    = {3,4,4,4};
__constant__ int c_aggoff[4] = {0,24000,264000,384000};
__constant__ int c_outoff[4] = {0,48000,528000,768000};
__constant__ int c_aggrows[4]= {24000,240000,120000,96000};
// per-dtype tile width (log2): SB=128, PQ=1024, PV=512, NB=512
__constant__ int c_lT[4] = {7,10,9,9};
__constant__ int c_tprefix[16] = {0,32,62,86,116,146,170,200,232,264,294,318,348,378,408,432};

typedef _Float16 f16x8 __attribute__((ext_vector_type(8)));
typedef float f32x4 __attribute__((ext_vector_type(4)));

__device__ __forceinline__ float eluf(float x){ return x > 0.0f ? x : expm1f(x); }
__device__ __forceinline__ float elufast(float x){ return x > 0.0f ? x : __expf(x)-1.0f; }
__device__ __forceinline__ unsigned encf(float f){ unsigned u=__float_as_uint(f); return (u&0x80000000u)? ~u : (u|0x80000000u); }
__device__ __forceinline__ float decf(unsigned u){ return __uint_as_float((u&0x80000000u)? (u^0x80000000u) : ~u); }
__device__ __forceinline__ float RL(float v, int l){ return __uint_as_float(__builtin_amdgcn_readlane(__float_as_uint(v), l)); }

__device__ __forceinline__ float dot128(const float* __restrict__ a, const float* __restrict__ b){
  const float4* a4 = (const float4*)a; const float4* b4 = (const float4*)b;
  float s = 0.f;
  #pragma unroll
  for (int h=0; h<32; h++){
    float4 A=a4[h], B=b4[h];
    s = fmaf(A.x,B.x,s); s = fmaf(A.y,B.y,s); s = fmaf(A.z,B.z,s); s = fmaf(A.w,B.w,s);
  }
  return s;
}
__device__ __forceinline__ void halfsum(const float* __restrict__ a, float& s0, float& s1){
  const float4* a4 = (const float4*)a;
  float x0=0.f, x1=0.f;
  #pragma unroll
  for (int h=0; h<16; h++){ float4 A=a4[h]; x0 += A.x+A.y+A.z+A.w; }
  #pragma unroll
  for (int h=16; h<32; h++){ float4 A=a4[h]; x1 += A.x+A.y+A.z+A.w; }
  s0=x0; s1=x1;
}

#define CHUNK 18750

// ---- fused front: build_x (blocks 0-59) | params (60-89) | count (90-209) ----
__global__ __launch_bounds__(1024) void k_front(
    const float* __restrict__ xSB, const float* __restrict__ cSB,
    const float* __restrict__ xPQ, const float* __restrict__ cPQ,
    const float* __restrict__ xPV, const float* __restrict__ cPV,
    const float* __restrict__ xNB, const float* __restrict__ cNB,
    const int* __restrict__ eidx,
    const float* __restrict__ Wq, const float* __restrict__ bq,
    const float* __restrict__ Wk, const float* __restrict__ bk,
    const float* __restrict__ Wv, const float* __restrict__ bv,
    const float* __restrict__ We, const float* __restrict__ be,
    const float* __restrict__ Ws, const float* __restrict__ bs,
    float* __restrict__ xall, float* __restrict__ par, int* __restrict__ gcnt8){
  const int b = blockIdx.x;
  if (b < 60){
    const int n = b*1024 + threadIdx.x;
    if (n >= 61000) return;
    const float *xp, *cp; int local;
    if (n < 4000)      { xp=xSB; cp=cSB; local=n; }
    else if (n < 34000){ xp=xPQ; cp=cPQ; local=n-4000; }
    else if (n < 49000){ xp=xPV; cp=cPV; local=n-34000; }
    else               { xp=xNB; cp=cNB; local=n-49000; }
    float4 a = ((const float4*)xp)[local];
    float4 bb = ((const float4*)cp)[local];
    ((float4*)xall)[n*2+0] = a;
    ((float4*)xall)[n*2+1] = bb;
  } else if (b < 90){
    const int c = b - 60, tid = threadIdx.x;
    if (tid >= 128) return;
    const float* wq = Wq + (size_t)c*1024;
    const float* wk = Wk + (size_t)c*1024;
    const float* wv = Wv + (size_t)c*1024;
    const float* ws = Ws + (size_t)c*1024;
    const float* we = We + (size_t)c*256;
    const float* vbq = bq + (size_t)c*128;
    const float* vbk = bk + (size_t)c*128;
    const float* vbv = bv + (size_t)c*128;
    const float* vbe = be + (size_t)c*128;
    const float* vbs = bs + (size_t)c*128;
    float* P = par + (size_t)c*160;
    if (tid < 64){
      int fd = tid>>3, fs = tid&7;
      P[tid] = dot128(wq + fd*128, wk + fs*128);
      return;
    }
    const int job = tid - 64, grp = job>>3, f = job&7;
    if (grp==0) P[64+f] = dot128(wq + f*128, vbk);
    else if (grp==1) P[72+f] = dot128(wk + f*128, vbq);
    else if (grp==2) P[80+f] = dot128(wq + f*128, we);
    else if (grp==3) P[88+f] = dot128(wq + f*128, we+128);
    else if (grp==4) P[96+f] = dot128(wq + f*128, vbe);
    else if (grp==5){ float s0,s1; halfsum(wv + f*128, s0,s1); P[104+f]=s0; P[112+f]=s1; }
    else if (grp==6){ float s0,s1; halfsum(ws + f*128, s0,s1); P[120+f]=s0; P[128+f]=s1; }
    else {
      if (f==0){ P[136] = dot128(vbq, vbk);
                 float a,bb; halfsum(vbs, a,bb); P[148]=a; P[149]=bb; }
      else if (f==1) P[137] = dot128(vbq, we);
      else if (f==2) P[138] = dot128(vbq, we+128);
      else if (f==3) P[139] = dot128(vbq, vbe);
      else if (f==4){ float a=0.f,bb=0.f; for(int h=0;h<64;h++){a+=we[h]; bb+=we[64+h];} P[140]=a; P[141]=bb; }
      else if (f==5){ float a=0.f,bb=0.f; for(int h=0;h<64;h++){a+=we[128+h]; bb+=we[192+h];} P[142]=a; P[143]=bb; }
      else if (f==6){ float a,bb; halfsum(vbv, a,bb); P[144]=a; P[145]=bb; }
      else          { float a,bb; halfsum(vbe, a,bb); P[146]=a; P[147]=bb; }
    }
  } else {
    const int cb = b - 90;
    const int t = cb / 8, chunk = cb % 8;
    const int lT = c_lT[c_dtype[t]];
    __shared__ int scnt[32];
    if (threadIdx.x < 32) scnt[threadIdx.x] = 0;
    __syncthreads();
    const int* __restrict__ dstp = eidx + (size_t)(t*2+1)*NE;
    const int e0 = chunk*CHUNK, e1 = min(NE, e0+CHUNK);
    for (int e=e0+threadIdx.x; e<e1; e+=1024) atomicAdd(&scnt[dstp[e]>>lT], 1);
    __syncthreads();
    if (threadIdx.x < 32) gcnt8[(t*8 + chunk)*32 + threadIdx.x] = scnt[threadIdx.x];
  }
}

// ---- scan: sum chunk counts -> gcnt/gofs/gcur; init mm. 1 block. ----
__global__ void k_scan(const int* __restrict__ gcnt8, int* __restrict__ gcnt,
                       int* __restrict__ gofs, int* __restrict__ gcur,
                       unsigned* __restrict__ mm){
  const int t = threadIdx.x;
  if (t == 16){ mm[0] = 0xFFFFFFFFu; }
  else if (t == 17){ mm[1] = 0u; }
  if (t >= 15) return;
  const int b0 = c_tprefix[t], b1 = c_tprefix[t+1];
  int run = t*NE;
  for (int b=b0; b<b1; b++){
    const int tile = b - b0;
    int c0 = 0;
    #pragma unroll
    for (int c=0; c<8; c++) c0 += gcnt8[(t*8 + c)*32 + tile];
    gcnt[b] = c0;
    gofs[b] = run; gcur[b] = run;
    run += c0;
  }
}

// ---- scatter+compute: does the FULL per-edge math (both layers) here, where
// 123K threads hide the two random xall reads. Emits {peA,peB,v01A,v01B}
// (uint4, 16B) + dl (4B) into balanced tile buckets. No downstream indirect
// loads or per-edge VALU remain. ----
__global__ __launch_bounds__(1024) void k_scatter(const int* __restrict__ eidx,
    const float* __restrict__ eattr, const float* __restrict__ xall,
    const float* __restrict__ par,
    int* __restrict__ gcur, uint4* __restrict__ ebufA, unsigned* __restrict__ ebufD){
  const int t = blockIdx.y;
  const int dt = c_dtype[t], st = c_stype[t];
  const int lT = c_lT[dt];
  const int tmask = (1<<lT) - 1;
  __shared__ int lcnt[32], lbase[32];
  __shared__ float sA[160], sB[160];
  if (threadIdx.x < 32) lcnt[threadIdx.x] = 0;
  if (threadIdx.x >= 64 && threadIdx.x < 224) sA[threadIdx.x-64] = par[(size_t)t*160 + threadIdx.x-64];
  if (threadIdx.x >= 224 && threadIdx.x < 384) sB[threadIdx.x-224] = par[(size_t)(15+t)*160 + threadIdx.x-224];
  __syncthreads();
  const int* __restrict__ dstp = eidx + (size_t)(t*2+1)*NE;
  const int* __restrict__ srcp = eidx + (size_t)(t*2)*NE;
  const float2* __restrict__ ea2 = (const float2*)eattr + (size_t)t*NE;
  const int e0 = blockIdx.x*CHUNK, e1 = min(NE, e0+CHUNK);
  for (int e=e0+threadIdx.x; e<e1; e+=1024) atomicAdd(&lcnt[dstp[e]>>lT], 1);
  __syncthreads();
  if (threadIdx.x < 32){
    int cchk = lcnt[threadIdx.x];
    lbase[threadIdx.x] = cchk > 0 ? atomicAdd(&gcur[c_tprefix[t]+threadIdx.x], cchk) : 0;
  }
  __syncthreads();
  if (threadIdx.x < 32) lcnt[threadIdx.x] = 0;
  __syncthreads();
  const int xod = c_xoff[dt], xos = c_xoff[st];
  const float SCALE = 0.08838834764831845f;
  for (int e=e0+threadIdx.x; e<e1; e+=1024){
    const int d = dstp[e];
    const int tile = d>>lT, dl = d & tmask;
    const int pos = lbase[tile] + atomicAdd(&lcnt[tile], 1);
    const float2 ea = ea2[e];
    const float4* xdp = (const float4*)(xall + (size_t)(xod+d)*8);
    const float4* xsp = (const float4*)(xall + (size_t)(xos+srcp[e])*8);
    const float4 d0v = xdp[0], d1v = xdp[1];
    const float4 s0v = xsp[0], s1v = xsp[1];
    float xd[8] = {d0v.x,d0v.y,d0v.z,d0v.w,d1v.x,d1v.y,d1v.z,d1v.w};
    float xs[8] = {s0v.x,s0v.y,s0v.z,s0v.w,s1v.x,s1v.y,s1v.z,s1v.w};
    // layer A
    float accA = sA[136], t0a = sA[137], t1a = sA[138], tba = sA[139];
    float accB = sB[136], t0b = sB[137], t1b = sB[138], tbb = sB[139];
    #pragma unroll
    for (int fd=0; fd<8; fd++){
      float ta = 0.f, tb2 = 0.f;
      #pragma unroll
      for (int fs=0; fs<8; fs++){ ta = fmaf(sA[fd*8+fs], xs[fs], ta); tb2 = fmaf(sB[fd*8+fs], xs[fs], tb2); }
      accA = fmaf(xd[fd], ta, accA);
      accB = fmaf(xd[fd], tb2, accB);
    }
    float v0A = fmaf(ea.x, sA[140], fmaf(ea.y, sA[142], sA[144]+sA[146]));
    float v1A = fmaf(ea.x, sA[141], fmaf(ea.y, sA[143], sA[145]+sA[147]));
    float v0B = fmaf(ea.x, sB[140], fmaf(ea.y, sB[142], sB[144]+sB[146]));
    float v1B = fmaf(ea.x, sB[141], fmaf(ea.y, sB[143], sB[145]+sB[147]));
    #pragma unroll
    for (int f=0; f<8; f++){
      accA = fmaf(xd[f], sA[64+f], accA);
      accA = fmaf(xs[f], sA[72+f], accA);
      t0a  = fmaf(xd[f], sA[80+f], t0a);
      t1a  = fmaf(xd[f], sA[88+f], t1a);
      tba  = fmaf(xd[f], sA[96+f], tba);
      v0A  = fmaf(xs[f], sA[104+f], v0A);
      v1A  = fmaf(xs[f], sA[112+f], v1A);
      accB = fmaf(xd[f], sB[64+f], accB);
      accB = fmaf(xs[f], sB[72+f], accB);
      t0b  = fmaf(xd[f], sB[80+f], t0b);
      t1b  = fmaf(xd[f], sB[88+f], t1b);
      tbb  = fmaf(xd[f], sB[96+f], tbb);
      v0B  = fmaf(xs[f], sB[104+f], v0B);
      v1B  = fmaf(xs[f], sB[112+f], v1B);
    }
    accA += fmaf(ea.x, t0a, fmaf(ea.y, t1a, tba));
    accB += fmaf(ea.x, t0b, fmaf(ea.y, t1b, tbb));
    const float peA = __expf(accA * SCALE);
    const float peB = __expf(accB * SCALE);
    __half2 hA = __floats2half2_rn(v0A, v1A);
    __half2 hB = __floats2half2_rn(v0B, v1B);
    ebufA[pos] = make_uint4(__float_as_uint(peA), __float_as_uint(peB),
                            *(unsigned*)&hA, *(unsigned*)&hB);
    ebufD[pos] = (unsigned)dl;
  }
}

// ---- reduce: per balanced bucket, stream records sequentially and
// accumulate 6 sums per row in LDS (24KB). Then finalize: softmax divide +
// skip + g write + minmax. Replaces tsort+gather; zero indirect loads. ----
__global__ __launch_bounds__(1024) void k_reduce(
    const uint4* __restrict__ ebufA, const unsigned* __restrict__ ebufD,
    const int* __restrict__ gofs, const int* __restrict__ gcnt,
    const float* __restrict__ xall, const float* __restrict__ par,
    const float* __restrict__ Wl, const float* __restrict__ bl,
    float* __restrict__ g, unsigned* __restrict__ mm){
  const int b = blockIdx.x;
  int t = 0;
  while (b >= c_tprefix[t+1]) ++t;
  const int tile = b - c_tprefix[t];
  const int dt = c_dtype[t];
  const int N = c_N[dt];
  const int lT = c_lT[dt];
  const int nbase = tile << lT;
  const int tileN = min(1<<lT, N - nbase);
  const int tid = threadIdx.x;

  __shared__ float ACC[6144];          // [row][6]
  __shared__ float sA[160], sB[160], wlb[192];
  __shared__ float smin[16], smax[16];

  for (int k=tid; k<6144; k+=1024) ACC[k] = 0.f;
  if (tid >= 64 && tid < 224) sA[tid-64] = par[(size_t)t*160 + tid-64];
  if (tid >= 224 && tid < 384) sB[tid-224] = par[(size_t)(15+t)*160 + tid-224];
  if (tid >= 384 && tid < 576){ int u=tid-384; wlb[u] = (u<128)? Wl[u] : bl[u-128]; }
  __syncthreads();

  const int start = gofs[b], count = gcnt[b];
  for (int k=tid; k<count; k+=1024){
    const unsigned dl = ebufD[start+k];
    const uint4 u4 = ebufA[start+k];
    const float peA = __uint_as_float(u4.x);
    const float peB = __uint_as_float(u4.y);
    const float2 vA = __half22float2(*(const __half2*)&u4.z);
    const float2 vB = __half22float2(*(const __half2*)&u4.w);
    float* a = &ACC[dl*6];
    atomicAdd(a+0, peA);
    atomicAdd(a+1, peA*vA.x);
    atomicAdd(a+2, peA*vA.y);
    atomicAdd(a+3, peB);
    atomicAdd(a+4, peB*vB.x);
    atomicAdd(a+5, peB*vB.y);
  }
  __syncthreads();

  float lmin = 3.4e38f, lmax = -3.4e38f;
  if (tid < tileN){
    const int n = nbase + tid;
    const float4* xdp = (const float4*)(xall + (size_t)(c_xoff[dt]+n)*8);
    const float4 b0v = xdp[0], b1v = xdp[1];
    float xd[8] = {b0v.x,b0v.y,b0v.z,b0v.w,b1v.x,b1v.y,b1v.z,b1v.w};
    const float* a = &ACC[tid*6];
    const float denA = a[0], n0A = a[1], n1A = a[2];
    const float denB = a[3], n0B = a[4], n1B = a[5];
    const float invA = 1.0f/(denA + 1e-16f);
    const float invB = 1.0f/(denB + 1e-16f);
    float s0a = fmaf(n0A, invA, sA[148]), s1a = fmaf(n1A, invA, sA[149]);
    float s0b = fmaf(n0B, invB, sB[148]), s1b = fmaf(n1B, invB, sB[149]);
    #pragma unroll
    for (int f=0;f<8;f++){
      s0a = fmaf(xd[f], sA[120+f], s0a); s1a = fmaf(xd[f], sA[128+f], s1a);
      s0b = fmaf(xd[f], sB[120+f], s0b); s1b = fmaf(xd[f], sB[128+f], s1b);
    }
    const int baseA = c_aggoff[dt] + (0*c_cnt[dt] + c_slot[t])*N + n;
    const int baseB = c_aggoff[dt] + (1*c_cnt[dt] + c_slot[t])*N + n;
    ((float2*)g)[baseA] = make_float2(s0a, s1a);
    ((float2*)g)[baseB] = make_float2(s0b, s1b);
    #pragma unroll
    for (int h=0;h<64;h++){
      float za = fmaf(s0a, wlb[h], fmaf(s1a, wlb[64+h], wlb[128+h]));
      float zb = fmaf(s0b, wlb[h], fmaf(s1b, wlb[64+h], wlb[128+h]));
      lmin = fminf(lmin, fminf(za,zb)); lmax = fmaxf(lmax, fmaxf(za,zb));
    }
  }
  #pragma unroll
  for (int m=32;m>=1;m>>=1){
    lmin = fminf(lmin, __shfl_xor(lmin,m));
    lmax = fmaxf(lmax, __shfl_xor(lmax,m));
  }
  const int wv = tid>>6;
  if ((tid&63)==0){ smin[wv]=lmin; smax[wv]=lmax; }
  __syncthreads();
  if (tid==0){
    float mn = smin[0], mx = smax[0];
    for (int k=1;k<16;k++){ mn = fminf(mn, smin[k]); mx = fmaxf(mx, smax[k]); }
    atomicMin(&mm[0], encf(mn));
    atomicMax(&mm[1], encf(mx));
  }
}

// ---- final: f16 MFMA matvec (layouts verified R11, absmax 0.031; R17 epilogue) ----
__global__ __launch_bounds__(256) void k_final(
    const float* __restrict__ g, const unsigned* __restrict__ mm,
    const float* __restrict__ Wl, const float* __restrict__ bl,
    const float* __restrict__ Wfc, const float* __restrict__ bfc,
    const float* __restrict__ Wl2, const float* __restrict__ bl2,
    float* __restrict__ out){
  const int gw = blockIdx.x*4 + (threadIdx.x>>6);   // global wave id, 64 rows each
  const int l  = threadIdx.x & 63;
  const int lr = l & 15, lg = l >> 4;
  int nt, wo;
  if (gw < 375)       { nt=0; wo=0; }
  else if (gw < 4125) { nt=1; wo=375; }
  else if (gw < 6000) { nt=2; wo=4125; }
  else                { nt=3; wo=6000; }
  const int R = c_aggrows[nt];
  const int r0 = (gw - wo)*64;
  const float zmin = decf(mm[0]), zmax = decf(mm[1]);
  const float rmin = 0.1f*eluf(zmin);
  const float rmax = 0.9f + 0.1f*eluf(zmax);
  const float s2 = 2.0f/(rmax - rmin + 1e-5f);
  const float cc = fmaf(-rmin, s2, -1.0f);
  float wl0v[2][8], wl1v[2][8], blv[2][8];
  #pragma unroll
  for (int kk=0; kk<2; kk++){
    const int hb = kk*32 + lg*8;
    const float4 a0 = *(const float4*)&Wl[hb],    a1 = *(const float4*)&Wl[hb+4];
    const float4 b0 = *(const float4*)&Wl[64+hb], b1 = *(const float4*)&Wl[64+hb+4];
    const float4 c0 = *(const float4*)&bl[hb],    c1 = *(const float4*)&bl[hb+4];
    wl0v[kk][0]=a0.x; wl0v[kk][1]=a0.y; wl0v[kk][2]=a0.z; wl0v[kk][3]=a0.w;
    wl0v[kk][4]=a1.x; wl0v[kk][5]=a1.y; wl0v[kk][6]=a1.z; wl0v[kk][7]=a1.w;
    wl1v[kk][0]=b0.x; wl1v[kk][1]=b0.y; wl1v[kk][2]=b0.z; wl1v[kk][3]=b0.w;
    wl1v[kk][4]=b1.x; wl1v[kk][5]=b1.y; wl1v[kk][6]=b1.z; wl1v[kk][7]=b1.w;
    blv[kk][0]=c0.x;  blv[kk][1]=c0.y;  blv[kk][2]=c0.z;  blv[kk][3]=c0.w;
    blv[kk][4]=c1.x;  blv[kk][5]=c1.y;  blv[kk][6]=c1.z;  blv[kk][7]=c1.w;
  }
  const float* __restrict__ W = Wfc + (size_t)nt*4096;
  f16x8 bfrag[2][4];
  #pragma unroll
  for (int kk=0; kk<2; kk++){
    #pragma unroll
    for (int ntl=0; ntl<4; ntl++){
      #pragma unroll
      for (int j=0; j<8; j++){
        const int h = kk*32 + lg*8 + j;
        bfrag[kk][ntl][j] = (_Float16)W[h*64 + ntl*16 + lr];
      }
    }
  }
  const float bf0 = bfc[nt*64 + lr],      bf1 = bfc[nt*64 + 16 + lr];
  const float bf2 = bfc[nt*64 + 32 + lr], bf3 = bfc[nt*64 + 48 + lr];
  const float2* __restrict__ g2p = (const float2*)g + c_aggoff[nt] + r0;
  const float wl20 = Wl2[l], wl21 = Wl2[64+l], bl2v = bl2[l];
  float* __restrict__ o1 = out + ((size_t)c_outoff[nt] + r0)*64 + l;
  float* __restrict__ o2 = o1 + (size_t)R*64;
  #pragma unroll
  for (int mt=0; mt<4; mt++){
    const float2 gv = g2p[mt*16 + lr];
    f16x8 af0, af1;
    #pragma unroll
    for (int j=0; j<8; j++){
      const float z0 = fmaf(gv.x, wl0v[0][j], fmaf(gv.y, wl1v[0][j], blv[0][j]));
      const float z1 = fmaf(gv.x, wl0v[1][j], fmaf(gv.y, wl1v[1][j], blv[1][j]));
      af0[j] = (_Float16)fmaf(elufast(z0), s2, cc);
      af1[j] = (_Float16)fmaf(elufast(z1), s2, cc);
    }
    f32x4 d0 = {0.f,0.f,0.f,0.f}, d1 = {0.f,0.f,0.f,0.f};
    f32x4 d2 = {0.f,0.f,0.f,0.f}, d3 = {0.f,0.f,0.f,0.f};
    d0 = __builtin_amdgcn_mfma_f32_16x16x32_f16(af0, bfrag[0][0], d0, 0,0,0);
    d1 = __builtin_amdgcn_mfma_f32_16x16x32_f16(af0, bfrag[0][1], d1, 0,0,0);
    d2 = __builtin_amdgcn_mfma_f32_16x16x32_f16(af0, bfrag[0][2], d2, 0,0,0);
    d3 = __builtin_amdgcn_mfma_f32_16x16x32_f16(af0, bfrag[0][3], d3, 0,0,0);
    d0 = __builtin_amdgcn_mfma_f32_16x16x32_f16(af1, bfrag[1][0], d0, 0,0,0);
    d1 = __builtin_amdgcn_mfma_f32_16x16x32_f16(af1, bfrag[1][1], d1, 0,0,0);
    d2 = __builtin_amdgcn_mfma_f32_16x16x32_f16(af1, bfrag[1][2], d2, 0,0,0);
    d3 = __builtin_amdgcn_mfma_f32_16x16x32_f16(af1, bfrag[1][3], d3, 0,0,0);
    float ph0[4], ph1[4];
    #pragma unroll
    for (int reg=0; reg<4; reg++){
      float p0 = elufast(d0[reg] + bf0) + elufast(d1[reg] + bf1);
      float p1 = elufast(d2[reg] + bf2) + elufast(d3[reg] + bf3);
      p0 += __shfl_xor(p0,1); p0 += __shfl_xor(p0,2); p0 += __shfl_xor(p0,4); p0 += __shfl_xor(p0,8);
      p1 += __shfl_xor(p1,1); p1 += __shfl_xor(p1,2); p1 += __shfl_xor(p1,4); p1 += __shfl_xor(p1,8);
      ph0[reg] = p0; ph1[reg] = p1;
    }
    #pragma unroll
    for (int rt=0; rt<16; rt++){
      const int r = mt*16 + rt;
      const float h0r = RL(ph0[rt&3], (rt>>2)<<4);
      const float h1r = RL(ph1[rt&3], (rt>>2)<<4);
      const float f = elufast(fmaf(h0r, wl20, fmaf(h1r, wl21, bl2v)));
      o1[(size_t)r*64] = f;
      o2[(size_t)r*64] = f;
    }
  }
}

extern "C" void kernel_launch(void* const* d_in, const int* in_sizes, int n_in,
                              void* d_out, int out_size, void* d_ws, size_t ws_size,
                              hipStream_t stream) {
  const float* xSB = (const float*)d_in[0];
  const float* cSB = (const float*)d_in[1];
  const float* xPQ = (const float*)d_in[2];
  const float* cPQ = (const float*)d_in[3];
  const float* xPV = (const float*)d_in[4];
  const float* cPV = (const float*)d_in[5];
  const float* xNB = (const float*)d_in[6];
  const float* cNB = (const float*)d_in[7];
  const int*   eidx = (const int*)d_in[8];
  const float* eattr= (const float*)d_in[9];
  const float* Wq = (const float*)d_in[10];
  const float* bq = (const float*)d_in[11];
  const float* Wk = (const float*)d_in[12];
  const float* bk = (const float*)d_in[13];
  const float* Wv = (const float*)d_in[14];
  const float* bv = (const float*)d_in[15];
  const float* We = (const float*)d_in[16];
  const float* be = (const float*)d_in[17];
  const float* Ws = (const float*)d_in[18];
  const float* bs = (const float*)d_in[19];
  const float* Wl = (const float*)d_in[20];
  const float* bl = (const float*)d_in[21];
  const float* Wfc= (const float*)d_in[22];
  const float* bfc= (const float*)d_in[23];
  const float* Wl2= (const float*)d_in[24];
  const float* bl2= (const float*)d_in[25];

  float* ws    = (float*)d_ws;
  float* xall  = ws + 0;                    // 488000 f
  float* par   = ws + 488000;               // 4800 f
  int* gcnt    = (int*)(ws + 492800);       // 432 i
  int* gofs    = (int*)(ws + 493232);       // 432 i
  int* gcur    = (int*)(ws + 493664);       // 432 i
  unsigned* mm = (unsigned*)(ws + 494096);  // 2
  int* gcnt8   = (int*)(ws + 494100);       // 3840 i
  uint4* ebufA = (uint4*)(ws + 497944);     // 2250000 uint4 (497944 % 4 == 0 -> 16B aligned)
  unsigned* ebufD = (unsigned*)(ws + 9497944); // 2250000 u32
  float* g     = ws + 11747944;             // 960000 f
  // end: 12707944 floats ~= 50.8 MB

  k_front<<<210, 1024, 0, stream>>>(xSB,cSB,xPQ,cPQ,xPV,cPV,xNB,cNB, eidx,
                                    Wq,bq,Wk,bk,Wv,bv,We,be,Ws,bs,
                                    xall, par, gcnt8);
  k_scan<<<1, 64, 0, stream>>>(gcnt8, gcnt, gofs, gcur, mm);
  dim3 gb(8, 15);
  k_scatter<<<gb, 1024, 0, stream>>>(eidx, eattr, xall, par, gcur, ebufA, ebufD);
  k_reduce<<<432, 1024, 0, stream>>>(ebufA, ebufD, gofs, gcnt, xall, par, Wl, bl, g, mm);
  k_final<<<1875, 256, 0, stream>>>(g, mm, Wl, bl, Wfc, bfc, Wl2, bl2, (float*)d_out);
}

// Round 20
// 468.896 us; speedup vs baseline: 1.3694x; 1.3694x over previous
//
#include <hip/hip_runtime.h>
#include <hip/hip_fp16.h>
#include <math.h>

#define NE 150000

// type ids: SB=0 PQ=1 PV=2 NB=3
__constant__ int c_stype[15] = {2,0,0,2,3,1,0,1,3,1,2,3,2,1,3};
__constant__ int c_dtype[15] = {0,1,3,1,1,3,2,0,0,2,3,2,2,1,3};
__constant__ int c_slot[15]  = {0,0,0,1,2,1,0,1,2,1,2,2,3,3,3};
__constant__ int c_N[4]      = {4000,30000,15000,12000};
__constant__ int c_xoff[4]   = {0,4000,34000,49000};
__constant__ int c_cnt[4]    = {3,4,4,4};
__constant__ int c_aggoff[4] = {0,24000,264000,384000};
__constant__ int c_outoff[4] = {0,48000,528000,768000};
__constant__ int c_aggrows[4]= {24000,240000,120000,96000};
// per-dtype tile width (log2): SB=128, PQ=1024, PV=512, NB=512
__constant__ int c_lT[4] = {7,10,9,9};
__constant__ int c_tprefix[16] = {0,32,62,86,116,146,170,200,232,264,294,318,348,378,408,432};

typedef _Float16 f16x8 __attribute__((ext_vector_type(8)));
typedef float f32x4 __attribute__((ext_vector_type(4)));

__device__ __forceinline__ float eluf(float x){ return x > 0.0f ? x : expm1f(x); }
__device__ __forceinline__ float elufast(float x){ return x > 0.0f ? x : __expf(x)-1.0f; }
__device__ __forceinline__ unsigned encf(float f){ unsigned u=__float_as_uint(f); return (u&0x80000000u)? ~u : (u|0x80000000u); }
__device__ __forceinline__ float decf(unsigned u){ return __uint_as_float((u&0x80000000u)? (u^0x80000000u) : ~u); }
__device__ __forceinline__ float RL(float v, int l){ return __uint_as_float(__builtin_amdgcn_readlane(__float_as_uint(v), l)); }

__device__ __forceinline__ float dot128(const float* __restrict__ a, const float* __restrict__ b){
  const float4* a4 = (const float4*)a; const float4* b4 = (const float4*)b;
  float s = 0.f;
  #pragma unroll
  for (int h=0; h<32; h++){
    float4 A=a4[h], B=b4[h];
    s = fmaf(A.x,B.x,s); s = fmaf(A.y,B.y,s); s = fmaf(A.z,B.z,s); s = fmaf(A.w,B.w,s);
  }
  return s;
}
__device__ __forceinline__ void halfsum(const float* __restrict__ a, float& s0, float& s1){
  const float4* a4 = (const float4*)a;
  float x0=0.f, x1=0.f;
  #pragma unroll
  for (int h=0; h<16; h++){ float4 A=a4[h]; x0 += A.x+A.y+A.z+A.w; }
  #pragma unroll
  for (int h=16; h<32; h++){ float4 A=a4[h]; x1 += A.x+A.y+A.z+A.w; }
  s0=x0; s1=x1;
}

#define CHUNK 18750

// ---- fused front: build_x (blocks 0-59) | params (60-89) | count (90-209) ----
__global__ __launch_bounds__(1024) void k_front(
    const float* __restrict__ xSB, const float* __restrict__ cSB,
    const float* __restrict__ xPQ, const float* __restrict__ cPQ,
    const float* __restrict__ xPV, const float* __restrict__ cPV,
    const float* __restrict__ xNB, const float* __restrict__ cNB,
    const int* __restrict__ eidx,
    const float* __restrict__ Wq, const float* __restrict__ bq,
    const float* __restrict__ Wk, const float* __restrict__ bk,
    const float* __restrict__ Wv, const float* __restrict__ bv,
    const float* __restrict__ We, const float* __restrict__ be,
    const float* __restrict__ Ws, const float* __restrict__ bs,
    float* __restrict__ xall, float* __restrict__ par, int* __restrict__ gcnt8){
  const int b = blockIdx.x;
  if (b < 60){
    const int n = b*1024 + threadIdx.x;
    if (n >= 61000) return;
    const float *xp, *cp; int local;
    if (n < 4000)      { xp=xSB; cp=cSB; local=n; }
    else if (n < 34000){ xp=xPQ; cp=cPQ; local=n-4000; }
    else if (n < 49000){ xp=xPV; cp=cPV; local=n-34000; }
    else               { xp=xNB; cp=cNB; local=n-49000; }
    float4 a = ((const float4*)xp)[local];
    float4 bb = ((const float4*)cp)[local];
    ((float4*)xall)[n*2+0] = a;
    ((float4*)xall)[n*2+1] = bb;
  } else if (b < 90){
    const int c = b - 60, tid = threadIdx.x;
    if (tid >= 128) return;
    const float* wq = Wq + (size_t)c*1024;
    const float* wk = Wk + (size_t)c*1024;
    const float* wv = Wv + (size_t)c*1024;
    const float* ws = Ws + (size_t)c*1024;
    const float* we = We + (size_t)c*256;
    const float* vbq = bq + (size_t)c*128;
    const float* vbk = bk + (size_t)c*128;
    const float* vbv = bv + (size_t)c*128;
    const float* vbe = be + (size_t)c*128;
    const float* vbs = bs + (size_t)c*128;
    float* P = par + (size_t)c*160;
    if (tid < 64){
      int fd = tid>>3, fs = tid&7;
      P[tid] = dot128(wq + fd*128, wk + fs*128);
      return;
    }
    const int job = tid - 64, grp = job>>3, f = job&7;
    if (grp==0) P[64+f] = dot128(wq + f*128, vbk);
    else if (grp==1) P[72+f] = dot128(wk + f*128, vbq);
    else if (grp==2) P[80+f] = dot128(wq + f*128, we);
    else if (grp==3) P[88+f] = dot128(wq + f*128, we+128);
    else if (grp==4) P[96+f] = dot128(wq + f*128, vbe);
    else if (grp==5){ float s0,s1; halfsum(wv + f*128, s0,s1); P[104+f]=s0; P[112+f]=s1; }
    else if (grp==6){ float s0,s1; halfsum(ws + f*128, s0,s1); P[120+f]=s0; P[128+f]=s1; }
    else {
      if (f==0){ P[136] = dot128(vbq, vbk);
                 float a,bb; halfsum(vbs, a,bb); P[148]=a; P[149]=bb; }
      else if (f==1) P[137] = dot128(vbq, we);
      else if (f==2) P[138] = dot128(vbq, we+128);
      else if (f==3) P[139] = dot128(vbq, vbe);
      else if (f==4){ float a=0.f,bb=0.f; for(int h=0;h<64;h++){a+=we[h]; bb+=we[64+h];} P[140]=a; P[141]=bb; }
      else if (f==5){ float a=0.f,bb=0.f; for(int h=0;h<64;h++){a+=we[128+h]; bb+=we[192+h];} P[142]=a; P[143]=bb; }
      else if (f==6){ float a,bb; halfsum(vbv, a,bb); P[144]=a; P[145]=bb; }
      else          { float a,bb; halfsum(vbe, a,bb); P[146]=a; P[147]=bb; }
    }
  } else {
    const int cb = b - 90;
    const int t = cb / 8, chunk = cb % 8;
    const int lT = c_lT[c_dtype[t]];
    __shared__ int scnt[32];
    if (threadIdx.x < 32) scnt[threadIdx.x] = 0;
    __syncthreads();
    const int* __restrict__ dstp = eidx + (size_t)(t*2+1)*NE;
    const int e0 = chunk*CHUNK, e1 = min(NE, e0+CHUNK);
    for (int e=e0+threadIdx.x; e<e1; e+=1024) atomicAdd(&scnt[dstp[e]>>lT], 1);
    __syncthreads();
    if (threadIdx.x < 32) gcnt8[(t*8 + chunk)*32 + threadIdx.x] = scnt[threadIdx.x];
  }
}

// ---- scan: sum chunk counts -> gcnt/gofs/gcur; init mm. 1 block. ----
__global__ void k_scan(const int* __restrict__ gcnt8, int* __restrict__ gcnt,
                       int* __restrict__ gofs, int* __restrict__ gcur,
                       unsigned* __restrict__ mm){
  const int t = threadIdx.x;
  if (t == 16){ mm[0] = 0xFFFFFFFFu; }
  else if (t == 17){ mm[1] = 0u; }
  if (t >= 15) return;
  const int b0 = c_tprefix[t], b1 = c_tprefix[t+1];
  int run = t*NE;
  for (int b=b0; b<b1; b++){
    const int tile = b - b0;
    int c0 = 0;
    #pragma unroll
    for (int c=0; c<8; c++) c0 += gcnt8[(t*8 + c)*32 + tile];
    gcnt[b] = c0;
    gofs[b] = run; gcur[b] = run;
    run += c0;
  }
}

// ---- scatter packed payload {src<<10|dl, ea f16x2} into balanced tile
// buckets (PROVEN cheap: streams only, 8B writes, no random reads). ----
__global__ __launch_bounds__(1024) void k_scatter(const int* __restrict__ eidx,
    const float* __restrict__ eattr,
    int* __restrict__ gcur, uint2* __restrict__ ebuf){
  const int t = blockIdx.y;
  const int lT = c_lT[c_dtype[t]];
  const int tmask = (1<<lT) - 1;
  __shared__ int lcnt[32], lbase[32];
  if (threadIdx.x < 32) lcnt[threadIdx.x] = 0;
  __syncthreads();
  const int* __restrict__ dstp = eidx + (size_t)(t*2+1)*NE;
  const int* __restrict__ srcp = eidx + (size_t)(t*2)*NE;
  const float2* __restrict__ ea2 = (const float2*)eattr + (size_t)t*NE;
  const int e0 = blockIdx.x*CHUNK, e1 = min(NE, e0+CHUNK);
  for (int e=e0+threadIdx.x; e<e1; e+=1024) atomicAdd(&lcnt[dstp[e]>>lT], 1);
  __syncthreads();
  if (threadIdx.x < 32){
    int cchk = lcnt[threadIdx.x];
    lbase[threadIdx.x] = cchk > 0 ? atomicAdd(&gcur[c_tprefix[t]+threadIdx.x], cchk) : 0;
  }
  __syncthreads();
  if (threadIdx.x < 32) lcnt[threadIdx.x] = 0;
  __syncthreads();
  for (int e=e0+threadIdx.x; e<e1; e+=1024){
    const int d = dstp[e];
    const int tile = d>>lT, dl = d & tmask;
    const int pos = lbase[tile] + atomicAdd(&lcnt[tile], 1);
    const float2 ea = ea2[e];
    __half2 h2 = __floats2half2_rn(ea.x, ea.y);
    ebuf[pos] = make_uint2(((unsigned)srcp[e]<<10) | (unsigned)dl, *(unsigned*)&h2);
  }
}

// ---- reduce: per balanced bucket, stream 8B records; per edge do FULL
// conv math (xd from L1-resident tile slice, xs from L2-resident xall) and
// LDS-atomicAdd 6 sums per row. Then finalize softmax+skip+g+minmax.
// Replaces tsort+gather: no permute, no serial per-node loops, pure TLP. ----
__global__ __launch_bounds__(1024) void k_reduce(
    const uint2* __restrict__ ebuf,
    const int* __restrict__ gofs, const int* __restrict__ gcnt,
    const float* __restrict__ xall, const float* __restrict__ par,
    const float* __restrict__ Wl, const float* __restrict__ bl,
    float* __restrict__ g, unsigned* __restrict__ mm){
  const int b = blockIdx.x;
  int t = 0;
  while (b >= c_tprefix[t+1]) ++t;
  const int tile = b - c_tprefix[t];
  const int dt = c_dtype[t], st = c_stype[t];
  const int N = c_N[dt];
  const int lT = c_lT[dt];
  const int nbase = tile << lT;
  const int tileN = min(1<<lT, N - nbase);
  const int tid = threadIdx.x;

  __shared__ float ACC[6144];          // [row][6]
  __shared__ float sA[160], sB[160], wlb[192];
  __shared__ float smin[16], smax[16];

  for (int k=tid; k<6144; k+=1024) ACC[k] = 0.f;
  if (tid >= 64 && tid < 224) sA[tid-64] = par[(size_t)t*160 + tid-64];
  if (tid >= 224 && tid < 384) sB[tid-224] = par[(size_t)(15+t)*160 + tid-224];
  if (tid >= 384 && tid < 576){ int u=tid-384; wlb[u] = (u<128)? Wl[u] : bl[u-128]; }
  __syncthreads();

  const int start = gofs[b], count = gcnt[b];
  const int xod = c_xoff[dt] + nbase, xos = c_xoff[st];
  const float SCALE = 0.08838834764831845f;
  for (int k=tid; k<count; k+=1024){
    const uint2 rec = ebuf[start+k];
    const int dl = rec.x & 1023u;
    const int src = rec.x >> 10;
    const float2 ea = __half22float2(*(const __half2*)&rec.y);
    const float4* xdp = (const float4*)(xall + (size_t)(xod+dl)*8);
    const float4* xsp = (const float4*)(xall + (size_t)(xos+src)*8);
    const float4 d0v = xdp[0], d1v = xdp[1];
    const float4 s0v = xsp[0], s1v = xsp[1];
    float xd[8] = {d0v.x,d0v.y,d0v.z,d0v.w,d1v.x,d1v.y,d1v.z,d1v.w};
    float xs[8] = {s0v.x,s0v.y,s0v.z,s0v.w,s1v.x,s1v.y,s1v.z,s1v.w};
    float accA = sA[136], t0a = sA[137], t1a = sA[138], tba = sA[139];
    float accB = sB[136], t0b = sB[137], t1b = sB[138], tbb = sB[139];
    #pragma unroll
    for (int fd=0; fd<8; fd++){
      float ta = 0.f, tb2 = 0.f;
      #pragma unroll
      for (int fs=0; fs<8; fs++){ ta = fmaf(sA[fd*8+fs], xs[fs], ta); tb2 = fmaf(sB[fd*8+fs], xs[fs], tb2); }
      accA = fmaf(xd[fd], ta, accA);
      accB = fmaf(xd[fd], tb2, accB);
    }
    float v0A = fmaf(ea.x, sA[140], fmaf(ea.y, sA[142], sA[144]+sA[146]));
    float v1A = fmaf(ea.x, sA[141], fmaf(ea.y, sA[143], sA[145]+sA[147]));
    float v0B = fmaf(ea.x, sB[140], fmaf(ea.y, sB[142], sB[144]+sB[146]));
    float v1B = fmaf(ea.x, sB[141], fmaf(ea.y, sB[143], sB[145]+sB[147]));
    #pragma unroll
    for (int f=0; f<8; f++){
      accA = fmaf(xd[f], sA[64+f], accA);
      accA = fmaf(xs[f], sA[72+f], accA);
      t0a  = fmaf(xd[f], sA[80+f], t0a);
      t1a  = fmaf(xd[f], sA[88+f], t1a);
      tba  = fmaf(xd[f], sA[96+f], tba);
      v0A  = fmaf(xs[f], sA[104+f], v0A);
      v1A  = fmaf(xs[f], sA[112+f], v1A);
      accB = fmaf(xd[f], sB[64+f], accB);
      accB = fmaf(xs[f], sB[72+f], accB);
      t0b  = fmaf(xd[f], sB[80+f], t0b);
      t1b  = fmaf(xd[f], sB[88+f], t1b);
      tbb  = fmaf(xd[f], sB[96+f], tbb);
      v0B  = fmaf(xs[f], sB[104+f], v0B);
      v1B  = fmaf(xs[f], sB[112+f], v1B);
    }
    accA += fmaf(ea.x, t0a, fmaf(ea.y, t1a, tba));
    accB += fmaf(ea.x, t0b, fmaf(ea.y, t1b, tbb));
    const float peA = __expf(accA * SCALE);
    const float peB = __expf(accB * SCALE);
    float* a = &ACC[dl*6];
    atomicAdd(a+0, peA);
    atomicAdd(a+1, peA*v0A);
    atomicAdd(a+2, peA*v1A);
    atomicAdd(a+3, peB);
    atomicAdd(a+4, peB*v0B);
    atomicAdd(a+5, peB*v1B);
  }
  __syncthreads();

  float lmin = 3.4e38f, lmax = -3.4e38f;
  if (tid < tileN){
    const int n = nbase + tid;
    const float4* xdp = (const float4*)(xall + (size_t)(c_xoff[dt]+n)*8);
    const float4 b0v = xdp[0], b1v = xdp[1];
    float xd[8] = {b0v.x,b0v.y,b0v.z,b0v.w,b1v.x,b1v.y,b1v.z,b1v.w};
    const float* a = &ACC[tid*6];
    const float denA = a[0], n0A = a[1], n1A = a[2];
    const float denB = a[3], n0B = a[4], n1B = a[5];
    const float invA = 1.0f/(denA + 1e-16f);
    const float invB = 1.0f/(denB + 1e-16f);
    float s0a = fmaf(n0A, invA, sA[148]), s1a = fmaf(n1A, invA, sA[149]);
    float s0b = fmaf(n0B, invB, sB[148]), s1b = fmaf(n1B, invB, sB[149]);
    #pragma unroll
    for (int f=0;f<8;f++){
      s0a = fmaf(xd[f], sA[120+f], s0a); s1a = fmaf(xd[f], sA[128+f], s1a);
      s0b = fmaf(xd[f], sB[120+f], s0b); s1b = fmaf(xd[f], sB[128+f], s1b);
    }
    const int baseA = c_aggoff[dt] + (0*c_cnt[dt] + c_slot[t])*N + n;
    const int baseB = c_aggoff[dt] + (1*c_cnt[dt] + c_slot[t])*N + n;
    ((float2*)g)[baseA] = make_float2(s0a, s1a);
    ((float2*)g)[baseB] = make_float2(s0b, s1b);
    #pragma unroll
    for (int h=0;h<64;h++){
      float za = fmaf(s0a, wlb[h], fmaf(s1a, wlb[64+h], wlb[128+h]));
      float zb = fmaf(s0b, wlb[h], fmaf(s1b, wlb[64+h], wlb[128+h]));
      lmin = fminf(lmin, fminf(za,zb)); lmax = fmaxf(lmax, fmaxf(za,zb));
    }
  }
  #pragma unroll
  for (int m=32;m>=1;m>>=1){
    lmin = fminf(lmin, __shfl_xor(lmin,m));
    lmax = fmaxf(lmax, __shfl_xor(lmax,m));
  }
  const int wv = tid>>6;
  if ((tid&63)==0){ smin[wv]=lmin; smax[wv]=lmax; }
  __syncthreads();
  if (tid==0){
    float mn = smin[0], mx = smax[0];
    for (int k=1;k<16;k++){ mn = fminf(mn, smin[k]); mx = fmaxf(mx, smax[k]); }
    atomicMin(&mm[0], encf(mn));
    atomicMax(&mm[1], encf(mx));
  }
}

// ---- final: f16 MFMA matvec (layouts verified R11, absmax 0.031) ----
__global__ __launch_bounds__(256) void k_final(
    const float* __restrict__ g, const unsigned* __restrict__ mm,
    const float* __restrict__ Wl, const float* __restrict__ bl,
    const float* __restrict__ Wfc, const float* __restrict__ bfc,
    const float* __restrict__ Wl2, const float* __restrict__ bl2,
    float* __restrict__ out){
  const int gw = blockIdx.x*4 + (threadIdx.x>>6);   // global wave id, 64 rows each
  const int l  = threadIdx.x & 63;
  const int lr = l & 15, lg = l >> 4;
  int nt, wo;
  if (gw < 375)       { nt=0; wo=0; }
  else if (gw < 4125) { nt=1; wo=375; }
  else if (gw < 6000) { nt=2; wo=4125; }
  else                { nt=3; wo=6000; }
  const int R = c_aggrows[nt];
  const int r0 = (gw - wo)*64;
  const float zmin = decf(mm[0]), zmax = decf(mm[1]);
  const float rmin = 0.1f*eluf(zmin);
  const float rmax = 0.9f + 0.1f*eluf(zmax);
  const float s2 = 2.0f/(rmax - rmin + 1e-5f);
  const float cc = fmaf(-rmin, s2, -1.0f);
  float wl0v[2][8], wl1v[2][8], blv[2][8];
  #pragma unroll
  for (int kk=0; kk<2; kk++){
    const int hb = kk*32 + lg*8;
    const float4 a0 = *(const float4*)&Wl[hb],    a1 = *(const float4*)&Wl[hb+4];
    const float4 b0 = *(const float4*)&Wl[64+hb], b1 = *(const float4*)&Wl[64+hb+4];
    const float4 c0 = *(const float4*)&bl[hb],    c1 = *(const float4*)&bl[hb+4];
    wl0v[kk][0]=a0.x; wl0v[kk][1]=a0.y; wl0v[kk][2]=a0.z; wl0v[kk][3]=a0.w;
    wl0v[kk][4]=a1.x; wl0v[kk][5]=a1.y; wl0v[kk][6]=a1.z; wl0v[kk][7]=a1.w;
    wl1v[kk][0]=b0.x; wl1v[kk][1]=b0.y; wl1v[kk][2]=b0.z; wl1v[kk][3]=b0.w;
    wl1v[kk][4]=b1.x; wl1v[kk][5]=b1.y; wl1v[kk][6]=b1.z; wl1v[kk][7]=b1.w;
    blv[kk][0]=c0.x;  blv[kk][1]=c0.y;  blv[kk][2]=c0.z;  blv[kk][3]=c0.w;
    blv[kk][4]=c1.x;  blv[kk][5]=c1.y;  blv[kk][6]=c1.z;  blv[kk][7]=c1.w;
  }
  const float* __restrict__ W = Wfc + (size_t)nt*4096;
  f16x8 bfrag[2][4];
  #pragma unroll
  for (int kk=0; kk<2; kk++){
    #pragma unroll
    for (int ntl=0; ntl<4; ntl++){
      #pragma unroll
      for (int j=0; j<8; j++){
        const int h = kk*32 + lg*8 + j;
        bfrag[kk][ntl][j] = (_Float16)W[h*64 + ntl*16 + lr];
      }
    }
  }
  const float bf0 = bfc[nt*64 + lr],      bf1 = bfc[nt*64 + 16 + lr];
  const float bf2 = bfc[nt*64 + 32 + lr], bf3 = bfc[nt*64 + 48 + lr];
  const float2* __restrict__ g2p = (const float2*)g + c_aggoff[nt] + r0;
  const float wl20 = Wl2[l], wl21 = Wl2[64+l], bl2v = bl2[l];
  float* __restrict__ o1 = out + ((size_t)c_outoff[nt] + r0)*64 + l;
  float* __restrict__ o2 = o1 + (size_t)R*64;
  #pragma unroll
  for (int mt=0; mt<4; mt++){
    const float2 gv = g2p[mt*16 + lr];
    f16x8 af0, af1;
    #pragma unroll
    for (int j=0; j<8; j++){
      const float z0 = fmaf(gv.x, wl0v[0][j], fmaf(gv.y, wl1v[0][j], blv[0][j]));
      const float z1 = fmaf(gv.x, wl0v[1][j], fmaf(gv.y, wl1v[1][j], blv[1][j]));
      af0[j] = (_Float16)fmaf(elufast(z0), s2, cc);
      af1[j] = (_Float16)fmaf(elufast(z1), s2, cc);
    }
    f32x4 d0 = {0.f,0.f,0.f,0.f}, d1 = {0.f,0.f,0.f,0.f};
    f32x4 d2 = {0.f,0.f,0.f,0.f}, d3 = {0.f,0.f,0.f,0.f};
    d0 = __builtin_amdgcn_mfma_f32_16x16x32_f16(af0, bfrag[0][0], d0, 0,0,0);
    d1 = __builtin_amdgcn_mfma_f32_16x16x32_f16(af0, bfrag[0][1], d1, 0,0,0);
    d2 = __builtin_amdgcn_mfma_f32_16x16x32_f16(af0, bfrag[0][2], d2, 0,0,0);
    d3 = __builtin_amdgcn_mfma_f32_16x16x32_f16(af0, bfrag[0][3], d3, 0,0,0);
    d0 = __builtin_amdgcn_mfma_f32_16x16x32_f16(af1, bfrag[1][0], d0, 0,0,0);
    d1 = __builtin_amdgcn_mfma_f32_16x16x32_f16(af1, bfrag[1][1], d1, 0,0,0);
    d2 = __builtin_amdgcn_mfma_f32_16x16x32_f16(af1, bfrag[1][2], d2, 0,0,0);
    d3 = __builtin_amdgcn_mfma_f32_16x16x32_f16(af1, bfrag[1][3], d3, 0,0,0);
    float ph0[4], ph1[4];
    #pragma unroll
    for (int reg=0; reg<4; reg++){
      float p0 = elufast(d0[reg] + bf0) + elufast(d1[reg] + bf1);
      float p1 = elufast(d2[reg] + bf2) + elufast(d3[reg] + bf3);
      p0 += __shfl_xor(p0,1); p0 += __shfl_xor(p0,2); p0 += __shfl_xor(p0,4); p0 += __shfl_xor(p0,8);
      p1 += __shfl_xor(p1,1); p1 += __shfl_xor(p1,2); p1 += __shfl_xor(p1,4); p1 += __shfl_xor(p1,8);
      ph0[reg] = p0; ph1[reg] = p1;
    }
    #pragma unroll
    for (int rt=0; rt<16; rt++){
      const int r = mt*16 + rt;
      const float h0r = RL(ph0[rt&3], (rt>>2)<<4);
      const float h1r = RL(ph1[rt&3], (rt>>2)<<4);
      const float f = elufast(fmaf(h0r, wl20, fmaf(h1r, wl21, bl2v)));
      o1[(size_t)r*64] = f;
      o2[(size_t)r*64] = f;
    }
  }
}

extern "C" void kernel_launch(void* const* d_in, const int* in_sizes, int n_in,
                              void* d_out, int out_size, void* d_ws, size_t ws_size,
                              hipStream_t stream) {
  const float* xSB = (const float*)d_in[0];
  const float* cSB = (const float*)d_in[1];
  const float* xPQ = (const float*)d_in[2];
  const float* cPQ = (const float*)d_in[3];
  const float* xPV = (const float*)d_in[4];
  const float* cPV = (const float*)d_in[5];
  const float* xNB = (const float*)d_in[6];
  const float* cNB = (const float*)d_in[7];
  const int*   eidx = (const int*)d_in[8];
  const float* eattr= (const float*)d_in[9];
  const float* Wq = (const float*)d_in[10];
  const float* bq = (const float*)d_in[11];
  const float* Wk = (const float*)d_in[12];
  const float* bk = (const float*)d_in[13];
  const float* Wv = (const float*)d_in[14];
  const float* bv = (const float*)d_in[15];
  const float* We = (const float*)d_in[16];
  const float* be = (const float*)d_in[17];
  const float* Ws = (const float*)d_in[18];
  const float* bs = (const float*)d_in[19];
  const float* Wl = (const float*)d_in[20];
  const float* bl = (const float*)d_in[21];
  const float* Wfc= (const float*)d_in[22];
  const float* bfc= (const float*)d_in[23];
  const float* Wl2= (const float*)d_in[24];
  const float* bl2= (const float*)d_in[25];

  float* ws    = (float*)d_ws;
  float* xall  = ws + 0;                    // 488000 f
  float* par   = ws + 488000;               // 4800 f
  int* gcnt    = (int*)(ws + 492800);       // 432 i
  int* gofs    = (int*)(ws + 493232);       // 432 i
  int* gcur    = (int*)(ws + 493664);       // 432 i
  unsigned* mm = (unsigned*)(ws + 494096);  // 2
  int* gcnt8   = (int*)(ws + 494100);       // 3840 i
  uint2* ebuf  = (uint2*)(ws + 497940);     // 2250000 uint2 (even offset -> 8B aligned)
  float* g     = ws + 4997940;              // 960000 f
  // end: 5957940 floats ~= 23.8 MB

  k_front<<<210, 1024, 0, stream>>>(xSB,cSB,xPQ,cPQ,xPV,cPV,xNB,cNB, eidx,
                                    Wq,bq,Wk,bk,Wv,bv,We,be,Ws,bs,
                                    xall, par, gcnt8);
  k_scan<<<1, 64, 0, stream>>>(gcnt8, gcnt, gofs, gcur, mm);
  dim3 gb(8, 15);
  k_scatter<<<gb, 1024, 0, stream>>>(eidx, eattr, gcur, ebuf);
  k_reduce<<<432, 1024, 0, stream>>>(ebuf, gofs, gcnt, xall, par, Wl, bl, g, mm);
  k_final<<<1875, 256, 0, stream>>>(g, mm, Wl, bl, Wfc, bfc, Wl2, bl2, (float*)d_out);
}

// Round 21
// 238.620 us; speedup vs baseline: 2.6909x; 1.9650x over previous
//
#include <hip/hip_runtime.h>
#include <hip/hip_fp16.h>
#include <math.h>

#define NE 150000

// type ids: SB=0 PQ=1 PV=2 NB=3
__constant__ int c_stype[15] = {2,0,0,2,3,1,0,1,3,1,2,3,2,1,3};
__constant__ int c_dtype[15] = {0,1,3,1,1,3,2,0,0,2,3,2,2,1,3};
__constant__ int c_slot[15]  = {0,0,0,1,2,1,0,1,2,1,2,2,3,3,3};
__constant__ int c_N[4]      = {4000,30000,15000,12000};
__constant__ int c_xoff[4]   = {0,4000,34000,49000};
__constant__ int c_cnt[4]    = {3,4,4,4};
__constant__ int c_aggoff[4] = {0,24000,264000,384000};
__constant__ int c_outoff[4] = {0,48000,528000,768000};
__constant__ int c_aggrows[4]= {24000,240000,120000,96000};
// per-dtype tile width (log2): SB=128, PQ=1024, PV=512, NB=512
__constant__ int c_lT[4] = {7,10,9,9};
__constant__ int c_tprefix[16] = {0,32,62,86,116,146,170,200,232,264,294,318,348,378,408,432};

typedef _Float16 f16x8 __attribute__((ext_vector_type(8)));
typedef float f32x4 __attribute__((ext_vector_type(4)));

__device__ __forceinline__ float eluf(float x){ return x > 0.0f ? x : expm1f(x); }
__device__ __forceinline__ float elufast(float x){ return x > 0.0f ? x : __expf(x)-1.0f; }
__device__ __forceinline__ unsigned encf(float f){ unsigned u=__float_as_uint(f); return (u&0x80000000u)? ~u : (u|0x80000000u); }
__device__ __forceinline__ float decf(unsigned u){ return __uint_as_float((u&0x80000000u)? (u^0x80000000u) : ~u); }
__device__ __forceinline__ float RL(float v, int l){ return __uint_as_float(__builtin_amdgcn_readlane(__float_as_uint(v), l)); }

__device__ __forceinline__ float dot128(const float* __restrict__ a, const float* __restrict__ b){
  const float4* a4 = (const float4*)a; const float4* b4 = (const float4*)b;
  float s = 0.f;
  #pragma unroll
  for (int h=0; h<32; h++){
    float4 A=a4[h], B=b4[h];
    s = fmaf(A.x,B.x,s); s = fmaf(A.y,B.y,s); s = fmaf(A.z,B.z,s); s = fmaf(A.w,B.w,s);
  }
  return s;
}
__device__ __forceinline__ void halfsum(const float* __restrict__ a, float& s0, float& s1){
  const float4* a4 = (const float4*)a;
  float x0=0.f, x1=0.f;
  #pragma unroll
  for (int h=0; h<16; h++){ float4 A=a4[h]; x0 += A.x+A.y+A.z+A.w; }
  #pragma unroll
  for (int h=16; h<32; h++){ float4 A=a4[h]; x1 += A.x+A.y+A.z+A.w; }
  s0=x0; s1=x1;
}

#define CHUNK 18750

// ---- fused front: build_x (blocks 0-59) | params (60-89) | count (90-209) ----
__global__ __launch_bounds__(1024) void k_front(
    const float* __restrict__ xSB, const float* __restrict__ cSB,
    const float* __restrict__ xPQ, const float* __restrict__ cPQ,
    const float* __restrict__ xPV, const float* __restrict__ cPV,
    const float* __restrict__ xNB, const float* __restrict__ cNB,
    const int* __restrict__ eidx,
    const float* __restrict__ Wq, const float* __restrict__ bq,
    const float* __restrict__ Wk, const float* __restrict__ bk,
    const float* __restrict__ Wv, const float* __restrict__ bv,
    const float* __restrict__ We, const float* __restrict__ be,
    const float* __restrict__ Ws, const float* __restrict__ bs,
    float* __restrict__ xall, float* __restrict__ par, int* __restrict__ gcnt8){
  const int b = blockIdx.x;
  if (b < 60){
    const int n = b*1024 + threadIdx.x;
    if (n >= 61000) return;
    const float *xp, *cp; int local;
    if (n < 4000)      { xp=xSB; cp=cSB; local=n; }
    else if (n < 34000){ xp=xPQ; cp=cPQ; local=n-4000; }
    else if (n < 49000){ xp=xPV; cp=cPV; local=n-34000; }
    else               { xp=xNB; cp=cNB; local=n-49000; }
    float4 a = ((const float4*)xp)[local];
    float4 bb = ((const float4*)cp)[local];
    ((float4*)xall)[n*2+0] = a;
    ((float4*)xall)[n*2+1] = bb;
  } else if (b < 90){
    const int c = b - 60, tid = threadIdx.x;
    if (tid >= 128) return;
    const float* wq = Wq + (size_t)c*1024;
    const float* wk = Wk + (size_t)c*1024;
    const float* wv = Wv + (size_t)c*1024;
    const float* ws = Ws + (size_t)c*1024;
    const float* we = We + (size_t)c*256;
    const float* vbq = bq + (size_t)c*128;
    const float* vbk = bk + (size_t)c*128;
    const float* vbv = bv + (size_t)c*128;
    const float* vbe = be + (size_t)c*128;
    const float* vbs = bs + (size_t)c*128;
    float* P = par + (size_t)c*160;
    if (tid < 64){
      int fd = tid>>3, fs = tid&7;
      P[tid] = dot128(wq + fd*128, wk + fs*128);
      return;
    }
    const int job = tid - 64, grp = job>>3, f = job&7;
    if (grp==0) P[64+f] = dot128(wq + f*128, vbk);
    else if (grp==1) P[72+f] = dot128(wk + f*128, vbq);
    else if (grp==2) P[80+f] = dot128(wq + f*128, we);
    else if (grp==3) P[88+f] = dot128(wq + f*128, we+128);
    else if (grp==4) P[96+f] = dot128(wq + f*128, vbe);
    else if (grp==5){ float s0,s1; halfsum(wv + f*128, s0,s1); P[104+f]=s0; P[112+f]=s1; }
    else if (grp==6){ float s0,s1; halfsum(ws + f*128, s0,s1); P[120+f]=s0; P[128+f]=s1; }
    else {
      if (f==0){ P[136] = dot128(vbq, vbk);
                 float a,bb; halfsum(vbs, a,bb); P[148]=a; P[149]=bb; }
      else if (f==1) P[137] = dot128(vbq, we);
      else if (f==2) P[138] = dot128(vbq, we+128);
      else if (f==3) P[139] = dot128(vbq, vbe);
      else if (f==4){ float a=0.f,bb=0.f; for(int h=0;h<64;h++){a+=we[h]; bb+=we[64+h];} P[140]=a; P[141]=bb; }
      else if (f==5){ float a=0.f,bb=0.f; for(int h=0;h<64;h++){a+=we[128+h]; bb+=we[192+h];} P[142]=a; P[143]=bb; }
      else if (f==6){ float a,bb; halfsum(vbv, a,bb); P[144]=a; P[145]=bb; }
      else          { float a,bb; halfsum(vbe, a,bb); P[146]=a; P[147]=bb; }
    }
  } else {
    const int cb = b - 90;
    const int t = cb / 8, chunk = cb % 8;
    const int lT = c_lT[c_dtype[t]];
    __shared__ int scnt[32];
    if (threadIdx.x < 32) scnt[threadIdx.x] = 0;
    __syncthreads();
    const int* __restrict__ dstp = eidx + (size_t)(t*2+1)*NE;
    const int e0 = chunk*CHUNK, e1 = min(NE, e0+CHUNK);
    for (int e=e0+threadIdx.x; e<e1; e+=1024) atomicAdd(&scnt[dstp[e]>>lT], 1);
    __syncthreads();
    if (threadIdx.x < 32) gcnt8[(t*8 + chunk)*32 + threadIdx.x] = scnt[threadIdx.x];
  }
}

// ---- scan: sum chunk counts -> gcnt/gofs/gcur; init mm. 1 block. ----
__global__ void k_scan(const int* __restrict__ gcnt8, int* __restrict__ gcnt,
                       int* __restrict__ gofs, int* __restrict__ gcur,
                       unsigned* __restrict__ mm){
  const int t = threadIdx.x;
  if (t == 16){ mm[0] = 0xFFFFFFFFu; }
  else if (t == 17){ mm[1] = 0u; }
  if (t >= 15) return;
  const int b0 = c_tprefix[t], b1 = c_tprefix[t+1];
  int run = t*NE;
  for (int b=b0; b<b1; b++){
    const int tile = b - b0;
    int c0 = 0;
    #pragma unroll
    for (int c=0; c<8; c++) c0 += gcnt8[(t*8 + c)*32 + tile];
    gcnt[b] = c0;
    gofs[b] = run; gcur[b] = run;
    run += c0;
  }
}

// ---- scatter packed payload {src<<10|dl, ea f16x2} into balanced tile
// buckets (PROVEN cheap: streams only, 8B writes, no random reads). ----
__global__ __launch_bounds__(1024) void k_scatter(const int* __restrict__ eidx,
    const float* __restrict__ eattr,
    int* __restrict__ gcur, uint2* __restrict__ ebuf){
  const int t = blockIdx.y;
  const int lT = c_lT[c_dtype[t]];
  const int tmask = (1<<lT) - 1;
  __shared__ int lcnt[32], lbase[32];
  if (threadIdx.x < 32) lcnt[threadIdx.x] = 0;
  __syncthreads();
  const int* __restrict__ dstp = eidx + (size_t)(t*2+1)*NE;
  const int* __restrict__ srcp = eidx + (size_t)(t*2)*NE;
  const float2* __restrict__ ea2 = (const float2*)eattr + (size_t)t*NE;
  const int e0 = blockIdx.x*CHUNK, e1 = min(NE, e0+CHUNK);
  for (int e=e0+threadIdx.x; e<e1; e+=1024) atomicAdd(&lcnt[dstp[e]>>lT], 1);
  __syncthreads();
  if (threadIdx.x < 32){
    int cchk = lcnt[threadIdx.x];
    lbase[threadIdx.x] = cchk > 0 ? atomicAdd(&gcur[c_tprefix[t]+threadIdx.x], cchk) : 0;
  }
  __syncthreads();
  if (threadIdx.x < 32) lcnt[threadIdx.x] = 0;
  __syncthreads();
  for (int e=e0+threadIdx.x; e<e1; e+=1024){
    const int d = dstp[e];
    const int tile = d>>lT, dl = d & tmask;
    const int pos = lbase[tile] + atomicAdd(&lcnt[tile], 1);
    const float2 ea = ea2[e];
    __half2 h2 = __floats2half2_rn(ea.x, ea.y);
    ebuf[pos] = make_uint2(((unsigned)srcp[e]<<10) | (unsigned)dl, *(unsigned*)&h2);
  }
}

// ---- reduce (512 threads -> VGPR cap 256, NO SPILL): per balanced bucket,
// stream 8B records; per edge do full conv math and LDS-atomicAdd 6 sums per
// row. Then finalize softmax+skip+g+minmax. ----
__global__ __launch_bounds__(512) void k_reduce(
    const uint2* __restrict__ ebuf,
    const int* __restrict__ gofs, const int* __restrict__ gcnt,
    const float* __restrict__ xall, const float* __restrict__ par,
    const float* __restrict__ Wl, const float* __restrict__ bl,
    float* __restrict__ g, unsigned* __restrict__ mm){
  const int b = blockIdx.x;
  int t = 0;
  while (b >= c_tprefix[t+1]) ++t;
  const int tile = b - c_tprefix[t];
  const int dt = c_dtype[t], st = c_stype[t];
  const int N = c_N[dt];
  const int lT = c_lT[dt];
  const int nbase = tile << lT;
  const int tileN = min(1<<lT, N - nbase);
  const int tid = threadIdx.x;

  __shared__ float ACC[6144];          // [row][6]
  __shared__ float sA[160], sB[160], wlb[192];
  __shared__ float smin[8], smax[8];

  for (int k=tid; k<6144; k+=512) ACC[k] = 0.f;
  if (tid < 160) sA[tid] = par[(size_t)t*160 + tid];
  else if (tid < 320) sB[tid-160] = par[(size_t)(15+t)*160 + tid-160];
  else if (tid < 512){ int u = tid-320; if (u < 192) wlb[u] = (u<128)? Wl[u] : bl[u-128]; }
  __syncthreads();

  const int start = gofs[b], count = gcnt[b];
  const int xod = c_xoff[dt] + nbase, xos = c_xoff[st];
  const float SCALE = 0.08838834764831845f;
  for (int k=tid; k<count; k+=512){
    const uint2 rec = ebuf[start+k];
    const int dl = rec.x & 1023u;
    const int src = rec.x >> 10;
    const float2 ea = __half22float2(*(const __half2*)&rec.y);
    const float4* xdp = (const float4*)(xall + (size_t)(xod+dl)*8);
    const float4* xsp = (const float4*)(xall + (size_t)(xos+src)*8);
    const float4 d0v = xdp[0], d1v = xdp[1];
    const float4 s0v = xsp[0], s1v = xsp[1];
    float xd[8] = {d0v.x,d0v.y,d0v.z,d0v.w,d1v.x,d1v.y,d1v.z,d1v.w};
    float xs[8] = {s0v.x,s0v.y,s0v.z,s0v.w,s1v.x,s1v.y,s1v.z,s1v.w};
    float accA = sA[136], t0a = sA[137], t1a = sA[138], tba = sA[139];
    float accB = sB[136], t0b = sB[137], t1b = sB[138], tbb = sB[139];
    #pragma unroll
    for (int fd=0; fd<8; fd++){
      float ta = 0.f, tb2 = 0.f;
      #pragma unroll
      for (int fs=0; fs<8; fs++){ ta = fmaf(sA[fd*8+fs], xs[fs], ta); tb2 = fmaf(sB[fd*8+fs], xs[fs], tb2); }
      accA = fmaf(xd[fd], ta, accA);
      accB = fmaf(xd[fd], tb2, accB);
    }
    float v0A = fmaf(ea.x, sA[140], fmaf(ea.y, sA[142], sA[144]+sA[146]));
    float v1A = fmaf(ea.x, sA[141], fmaf(ea.y, sA[143], sA[145]+sA[147]));
    float v0B = fmaf(ea.x, sB[140], fmaf(ea.y, sB[142], sB[144]+sB[146]));
    float v1B = fmaf(ea.x, sB[141], fmaf(ea.y, sB[143], sB[145]+sB[147]));
    #pragma unroll
    for (int f=0; f<8; f++){
      accA = fmaf(xd[f], sA[64+f], accA);
      accA = fmaf(xs[f], sA[72+f], accA);
      t0a  = fmaf(xd[f], sA[80+f], t0a);
      t1a  = fmaf(xd[f], sA[88+f], t1a);
      tba  = fmaf(xd[f], sA[96+f], tba);
      v0A  = fmaf(xs[f], sA[104+f], v0A);
      v1A  = fmaf(xs[f], sA[112+f], v1A);
      accB = fmaf(xd[f], sB[64+f], accB);
      accB = fmaf(xs[f], sB[72+f], accB);
      t0b  = fmaf(xd[f], sB[80+f], t0b);
      t1b  = fmaf(xd[f], sB[88+f], t1b);
      tbb  = fmaf(xd[f], sB[96+f], tbb);
      v0B  = fmaf(xs[f], sB[104+f], v0B);
      v1B  = fmaf(xs[f], sB[112+f], v1B);
    }
    accA += fmaf(ea.x, t0a, fmaf(ea.y, t1a, tba));
    accB += fmaf(ea.x, t0b, fmaf(ea.y, t1b, tbb));
    const float peA = __expf(accA * SCALE);
    const float peB = __expf(accB * SCALE);
    float* a = &ACC[dl*6];
    atomicAdd(a+0, peA);
    atomicAdd(a+1, peA*v0A);
    atomicAdd(a+2, peA*v1A);
    atomicAdd(a+3, peB);
    atomicAdd(a+4, peB*v0B);
    atomicAdd(a+5, peB*v1B);
  }
  __syncthreads();

  float lmin = 3.4e38f, lmax = -3.4e38f;
  for (int n0=tid; n0<tileN; n0+=512){
    const int n = nbase + n0;
    const float4* xdp = (const float4*)(xall + (size_t)(c_xoff[dt]+n)*8);
    const float4 b0v = xdp[0], b1v = xdp[1];
    float xd[8] = {b0v.x,b0v.y,b0v.z,b0v.w,b1v.x,b1v.y,b1v.z,b1v.w};
    const float* a = &ACC[n0*6];
    const float denA = a[0], n0A = a[1], n1A = a[2];
    const float denB = a[3], n0B = a[4], n1B = a[5];
    const float invA = 1.0f/(denA + 1e-16f);
    const float invB = 1.0f/(denB + 1e-16f);
    float s0a = fmaf(n0A, invA, sA[148]), s1a = fmaf(n1A, invA, sA[149]);
    float s0b = fmaf(n0B, invB, sB[148]), s1b = fmaf(n1B, invB, sB[149]);
    #pragma unroll
    for (int f=0;f<8;f++){
      s0a = fmaf(xd[f], sA[120+f], s0a); s1a = fmaf(xd[f], sA[128+f], s1a);
      s0b = fmaf(xd[f], sB[120+f], s0b); s1b = fmaf(xd[f], sB[128+f], s1b);
    }
    const int baseA = c_aggoff[dt] + (0*c_cnt[dt] + c_slot[t])*N + n;
    const int baseB = c_aggoff[dt] + (1*c_cnt[dt] + c_slot[t])*N + n;
    ((float2*)g)[baseA] = make_float2(s0a, s1a);
    ((float2*)g)[baseB] = make_float2(s0b, s1b);
    #pragma unroll
    for (int h=0;h<64;h++){
      float za = fmaf(s0a, wlb[h], fmaf(s1a, wlb[64+h], wlb[128+h]));
      float zb = fmaf(s0b, wlb[h], fmaf(s1b, wlb[64+h], wlb[128+h]));
      lmin = fminf(lmin, fminf(za,zb)); lmax = fmaxf(lmax, fmaxf(za,zb));
    }
  }
  #pragma unroll
  for (int m=32;m>=1;m>>=1){
    lmin = fminf(lmin, __shfl_xor(lmin,m));
    lmax = fmaxf(lmax, __shfl_xor(lmax,m));
  }
  const int wv = tid>>6;
  if ((tid&63)==0){ smin[wv]=lmin; smax[wv]=lmax; }
  __syncthreads();
  if (tid==0){
    float mn = smin[0], mx = smax[0];
    for (int k=1;k<8;k++){ mn = fminf(mn, smin[k]); mx = fmaxf(mx, smax[k]); }
    atomicMin(&mm[0], encf(mn));
    atomicMax(&mm[1], encf(mx));
  }
}

// ---- final: f16 MFMA matvec (layouts verified R11, absmax 0.031) ----
__global__ __launch_bounds__(256) void k_final(
    const float* __restrict__ g, const unsigned* __restrict__ mm,
    const float* __restrict__ Wl, const float* __restrict__ bl,
    const float* __restrict__ Wfc, const float* __restrict__ bfc,
    const float* __restrict__ Wl2, const float* __restrict__ bl2,
    float* __restrict__ out){
  const int gw = blockIdx.x*4 + (threadIdx.x>>6);   // global wave id, 64 rows each
  const int l  = threadIdx.x & 63;
  const int lr = l & 15, lg = l >> 4;
  int nt, wo;
  if (gw < 375)       { nt=0; wo=0; }
  else if (gw < 4125) { nt=1; wo=375; }
  else if (gw < 6000) { nt=2; wo=4125; }
  else                { nt=3; wo=6000; }
  const int R = c_aggrows[nt];
  const int r0 = (gw - wo)*64;
  const float zmin = decf(mm[0]), zmax = decf(mm[1]);
  const float rmin = 0.1f*eluf(zmin);
  const float rmax = 0.9f + 0.1f*eluf(zmax);
  const float s2 = 2.0f/(rmax - rmin + 1e-5f);
  const float cc = fmaf(-rmin, s2, -1.0f);
  float wl0v[2][8], wl1v[2][8], blv[2][8];
  #pragma unroll
  for (int kk=0; kk<2; kk++){
    const int hb = kk*32 + lg*8;
    const float4 a0 = *(const float4*)&Wl[hb],    a1 = *(const float4*)&Wl[hb+4];
    const float4 b0 = *(const float4*)&Wl[64+hb], b1 = *(const float4*)&Wl[64+hb+4];
    const float4 c0 = *(const float4*)&bl[hb],    c1 = *(const float4*)&bl[hb+4];
    wl0v[kk][0]=a0.x; wl0v[kk][1]=a0.y; wl0v[kk][2]=a0.z; wl0v[kk][3]=a0.w;
    wl0v[kk][4]=a1.x; wl0v[kk][5]=a1.y; wl0v[kk][6]=a1.z; wl0v[kk][7]=a1.w;
    wl1v[kk][0]=b0.x; wl1v[kk][1]=b0.y; wl1v[kk][2]=b0.z; wl1v[kk][3]=b0.w;
    wl1v[kk][4]=b1.x; wl1v[kk][5]=b1.y; wl1v[kk][6]=b1.z; wl1v[kk][7]=b1.w;
    blv[kk][0]=c0.x;  blv[kk][1]=c0.y;  blv[kk][2]=c0.z;  blv[kk][3]=c0.w;
    blv[kk][4]=c1.x;  blv[kk][5]=c1.y;  blv[kk][6]=c1.z;  blv[kk][7]=c1.w;
  }
  const float* __restrict__ W = Wfc + (size_t)nt*4096;
  f16x8 bfrag[2][4];
  #pragma unroll
  for (int kk=0; kk<2; kk++){
    #pragma unroll
    for (int ntl=0; ntl<4; ntl++){
      #pragma unroll
      for (int j=0; j<8; j++){
        const int h = kk*32 + lg*8 + j;
        bfrag[kk][ntl][j] = (_Float16)W[h*64 + ntl*16 + lr];
      }
    }
  }
  const float bf0 = bfc[nt*64 + lr],      bf1 = bfc[nt*64 + 16 + lr];
  const float bf2 = bfc[nt*64 + 32 + lr], bf3 = bfc[nt*64 + 48 + lr];
  const float2* __restrict__ g2p = (const float2*)g + c_aggoff[nt] + r0;
  const float wl20 = Wl2[l], wl21 = Wl2[64+l], bl2v = bl2[l];
  float* __restrict__ o1 = out + ((size_t)c_outoff[nt] + r0)*64 + l;
  float* __restrict__ o2 = o1 + (size_t)R*64;
  #pragma unroll
  for (int mt=0; mt<4; mt++){
    const float2 gv = g2p[mt*16 + lr];
    f16x8 af0, af1;
    #pragma unroll
    for (int j=0; j<8; j++){
      const float z0 = fmaf(gv.x, wl0v[0][j], fmaf(gv.y, wl1v[0][j], blv[0][j]));
      const float z1 = fmaf(gv.x, wl0v[1][j], fmaf(gv.y, wl1v[1][j], blv[1][j]));
      af0[j] = (_Float16)fmaf(elufast(z0), s2, cc);
      af1[j] = (_Float16)fmaf(elufast(z1), s2, cc);
    }
    f32x4 d0 = {0.f,0.f,0.f,0.f}, d1 = {0.f,0.f,0.f,0.f};
    f32x4 d2 = {0.f,0.f,0.f,0.f}, d3 = {0.f,0.f,0.f,0.f};
    d0 = __builtin_amdgcn_mfma_f32_16x16x32_f16(af0, bfrag[0][0], d0, 0,0,0);
    d1 = __builtin_amdgcn_mfma_f32_16x16x32_f16(af0, bfrag[0][1], d1, 0,0,0);
    d2 = __builtin_amdgcn_mfma_f32_16x16x32_f16(af0, bfrag[0][2], d2, 0,0,0);
    d3 = __builtin_amdgcn_mfma_f32_16x16x32_f16(af0, bfrag[0][3], d3, 0,0,0);
    d0 = __builtin_amdgcn_mfma_f32_16x16x32_f16(af1, bfrag[1][0], d0, 0,0,0);
    d1 = __builtin_amdgcn_mfma_f32_16x16x32_f16(af1, bfrag[1][1], d1, 0,0,0);
    d2 = __builtin_amdgcn_mfma_f32_16x16x32_f16(af1, bfrag[1][2], d2, 0,0,0);
    d3 = __builtin_amdgcn_mfma_f32_16x16x32_f16(af1, bfrag[1][3], d3, 0,0,0);
    float ph0[4], ph1[4];
    #pragma unroll
    for (int reg=0; reg<4; reg++){
      float p0 = elufast(d0[reg] + bf0) + elufast(d1[reg] + bf1);
      float p1 = elufast(d2[reg] + bf2) + elufast(d3[reg] + bf3);
      p0 += __shfl_xor(p0,1); p0 += __shfl_xor(p0,2); p0 += __shfl_xor(p0,4); p0 += __shfl_xor(p0,8);
      p1 += __shfl_xor(p1,1); p1 += __shfl_xor(p1,2); p1 += __shfl_xor(p1,4); p1 += __shfl_xor(p1,8);
      ph0[reg] = p0; ph1[reg] = p1;
    }
    #pragma unroll
    for (int rt=0; rt<16; rt++){
      const int r = mt*16 + rt;
      const float h0r = RL(ph0[rt&3], (rt>>2)<<4);
      const float h1r = RL(ph1[rt&3], (rt>>2)<<4);
      const float f = elufast(fmaf(h0r, wl20, fmaf(h1r, wl21, bl2v)));
      o1[(size_t)r*64] = f;
      o2[(size_t)r*64] = f;
    }
  }
}

extern "C" void kernel_launch(void* const* d_in, const int* in_sizes, int n_in,
                              void* d_out, int out_size, void* d_ws, size_t ws_size,
                              hipStream_t stream) {
  const float* xSB = (const float*)d_in[0];
  const float* cSB = (const float*)d_in[1];
  const float* xPQ = (const float*)d_in[2];
  const float* cPQ = (const float*)d_in[3];
  const float* xPV = (const float*)d_in[4];
  const float* cPV = (const float*)d_in[5];
  const float* xNB = (const float*)d_in[6];
  const float* cNB = (const float*)d_in[7];
  const int*   eidx = (const int*)d_in[8];
  const float* eattr= (const float*)d_in[9];
  const float* Wq = (const float*)d_in[10];
  const float* bq = (const float*)d_in[11];
  const float* Wk = (const float*)d_in[12];
  const float* bk = (const float*)d_in[13];
  const float* Wv = (const float*)d_in[14];
  const float* bv = (const float*)d_in[15];
  const float* We = (const float*)d_in[16];
  const float* be = (const float*)d_in[17];
  const float* Ws = (const float*)d_in[18];
  const float* bs = (const float*)d_in[19];
  const float* Wl = (const float*)d_in[20];
  const float* bl = (const float*)d_in[21];
  const float* Wfc= (const float*)d_in[22];
  const float* bfc= (const float*)d_in[23];
  const float* Wl2= (const float*)d_in[24];
  const float* bl2= (const float*)d_in[25];

  float* ws    = (float*)d_ws;
  float* xall  = ws + 0;                    // 488000 f
  float* par   = ws + 488000;               // 4800 f
  int* gcnt    = (int*)(ws + 492800);       // 432 i
  int* gofs    = (int*)(ws + 493232);       // 432 i
  int* gcur    = (int*)(ws + 493664);       // 432 i
  unsigned* mm = (unsigned*)(ws + 494096);  // 2
  int* gcnt8   = (int*)(ws + 494100);       // 3840 i
  uint2* ebuf  = (uint2*)(ws + 497940);     // 2250000 uint2 (even offset -> 8B aligned)
  float* g     = ws + 4997940;              // 960000 f
  // end: 5957940 floats ~= 23.8 MB

  k_front<<<210, 1024, 0, stream>>>(xSB,cSB,xPQ,cPQ,xPV,cPV,xNB,cNB, eidx,
                                    Wq,bq,Wk,bk,Wv,bv,We,be,Ws,bs,
                                    xall, par, gcnt8);
  k_scan<<<1, 64, 0, stream>>>(gcnt8, gcnt, gofs, gcur, mm);
  dim3 gb(8, 15);
  k_scatter<<<gb, 1024, 0, stream>>>(eidx, eattr, gcur, ebuf);
  k_reduce<<<432, 512, 0, stream>>>(ebuf, gofs, gcnt, xall, par, Wl, bl, g, mm);
  k_final<<<1875, 256, 0, stream>>>(g, mm, Wl, bl, Wfc, bfc, Wl2, bl2, (float*)d_out);
}

// Round 22
// 207.292 us; speedup vs baseline: 3.0976x; 1.1511x over previous
//
#include <hip/hip_runtime.h>
#include <hip/hip_fp16.h>
#include <math.h>

#define NE 150000

// type ids: SB=0 PQ=1 PV=2 NB=3
__constant__ int c_stype[15] = {2,0,0,2,3,1,0,1,3,1,2,3,2,1,3};
__constant__ int c_dtype[15] = {0,1,3,1,1,3,2,0,0,2,3,2,2,1,3};
__constant__ int c_slot[15]  = {0,0,0,1,2,1,0,1,2,1,2,2,3,3,3};
__constant__ int c_N[4]      = {4000,30000,15000,12000};
__constant__ int c_xoff[4]   = {0,4000,34000,49000};
__constant__ int c_cnt[4]    = {3,4,4,4};
__constant__ int c_aggoff[4] = {0,24000,264000,384000};
__constant__ int c_outoff[4] = {0,48000,528000,768000};
__constant__ int c_aggrows[4]= {24000,240000,120000,96000};
// per-dtype tile width (log2): SB=128, PQ=1024, PV=512, NB=512
// -> edges/bucket ~4.7-6.4K, uniform. 432 buckets total.
__constant__ int c_lT[4] = {7,10,9,9};
__constant__ int c_tprefix[16] = {0,32,62,86,116,146,170,200,232,264,294,318,348,378,408,432};
// per-type row-meta offsets (stride N+1, slack unused)
__constant__ int c_toff2[15] = {0,4001,34002,46003,76004,106005,118006,133007,137008,141009,156010,168011,183012,198013,228014};

typedef _Float16 f16x8 __attribute__((ext_vector_type(8)));
typedef float f32x4 __attribute__((ext_vector_type(4)));

__device__ __forceinline__ float eluf(float x){ return x > 0.0f ? x : expm1f(x); }
__device__ __forceinline__ float elufast(float x){ return x > 0.0f ? x : __expf(x)-1.0f; }
__device__ __forceinline__ unsigned encf(float f){ unsigned u=__float_as_uint(f); return (u&0x80000000u)? ~u : (u|0x80000000u); }
__device__ __forceinline__ float decf(unsigned u){ return __uint_as_float((u&0x80000000u)? (u^0x80000000u) : ~u); }
__device__ __forceinline__ float RL(float v, int l){ return __uint_as_float(__builtin_amdgcn_readlane(__float_as_uint(v), l)); }

__device__ __forceinline__ float dot128(const float* __restrict__ a, const float* __restrict__ b){
  const float4* a4 = (const float4*)a; const float4* b4 = (const float4*)b;
  float s = 0.f;
  #pragma unroll
  for (int h=0; h<32; h++){
    float4 A=a4[h], B=b4[h];
    s = fmaf(A.x,B.x,s); s = fmaf(A.y,B.y,s); s = fmaf(A.z,B.z,s); s = fmaf(A.w,B.w,s);
  }
  return s;
}
__device__ __forceinline__ void halfsum(const float* __restrict__ a, float& s0, float& s1){
  const float4* a4 = (const float4*)a;
  float x0=0.f, x1=0.f;
  #pragma unroll
  for (int h=0; h<16; h++){ float4 A=a4[h]; x0 += A.x+A.y+A.z+A.w; }
  #pragma unroll
  for (int h=16; h<32; h++){ float4 A=a4[h]; x1 += A.x+A.y+A.z+A.w; }
  s0=x0; s1=x1;
}

#define CHUNK 18750

// ---- fused front: build_x (blocks 0-59) | params (60-89) | count (90-209) ----
// count blocks write per-(type,chunk) slots unconditionally -> no init, no atomics.
__global__ __launch_bounds__(1024) void k_front(
    const float* __restrict__ xSB, const float* __restrict__ cSB,
    const float* __restrict__ xPQ, const float* __restrict__ cPQ,
    const float* __restrict__ xPV, const float* __restrict__ cPV,
    const float* __restrict__ xNB, const float* __restrict__ cNB,
    const int* __restrict__ eidx,
    const float* __restrict__ Wq, const float* __restrict__ bq,
    const float* __restrict__ Wk, const float* __restrict__ bk,
    const float* __restrict__ Wv, const float* __restrict__ bv,
    const float* __restrict__ We, const float* __restrict__ be,
    const float* __restrict__ Ws, const float* __restrict__ bs,
    float* __restrict__ xall, float* __restrict__ par, int* __restrict__ gcnt8){
  const int b = blockIdx.x;
  if (b < 60){
    const int n = b*1024 + threadIdx.x;
    if (n >= 61000) return;
    const float *xp, *cp; int local;
    if (n < 4000)      { xp=xSB; cp=cSB; local=n; }
    else if (n < 34000){ xp=xPQ; cp=cPQ; local=n-4000; }
    else if (n < 49000){ xp=xPV; cp=cPV; local=n-34000; }
    else               { xp=xNB; cp=cNB; local=n-49000; }
    float4 a = ((const float4*)xp)[local];
    float4 bb = ((const float4*)cp)[local];
    ((float4*)xall)[n*2+0] = a;
    ((float4*)xall)[n*2+1] = bb;
  } else if (b < 90){
    const int c = b - 60, tid = threadIdx.x;
    if (tid >= 128) return;
    const float* wq = Wq + (size_t)c*1024;
    const float* wk = Wk + (size_t)c*1024;
    const float* wv = Wv + (size_t)c*1024;
    const float* ws = Ws + (size_t)c*1024;
    const float* we = We + (size_t)c*256;
    const float* vbq = bq + (size_t)c*128;
    const float* vbk = bk + (size_t)c*128;
    const float* vbv = bv + (size_t)c*128;
    const float* vbe = be + (size_t)c*128;
    const float* vbs = bs + (size_t)c*128;
    float* P = par + (size_t)c*160;
    if (tid < 64){
      int fd = tid>>3, fs = tid&7;
      P[tid] = dot128(wq + fd*128, wk + fs*128);
      return;
    }
    const int job = tid - 64, grp = job>>3, f = job&7;
    if (grp==0) P[64+f] = dot128(wq + f*128, vbk);
    else if (grp==1) P[72+f] = dot128(wk + f*128, vbq);
    else if (grp==2) P[80+f] = dot128(wq + f*128, we);
    else if (grp==3) P[88+f] = dot128(wq + f*128, we+128);
    else if (grp==4) P[96+f] = dot128(wq + f*128, vbe);
    else if (grp==5){ float s0,s1; halfsum(wv + f*128, s0,s1); P[104+f]=s0; P[112+f]=s1; }
    else if (grp==6){ float s0,s1; halfsum(ws + f*128, s0,s1); P[120+f]=s0; P[128+f]=s1; }
    else {
      if (f==0){ P[136] = dot128(vbq, vbk);
                 float a,bb; halfsum(vbs, a,bb); P[148]=a; P[149]=bb; }
      else if (f==1) P[137] = dot128(vbq, we);
      else if (f==2) P[138] = dot128(vbq, we+128);
      else if (f==3) P[139] = dot128(vbq, vbe);
      else if (f==4){ float a=0.f,bb=0.f; for(int h=0;h<64;h++){a+=we[h]; bb+=we[64+h];} P[140]=a; P[141]=bb; }
      else if (f==5){ float a=0.f,bb=0.f; for(int h=0;h<64;h++){a+=we[128+h]; bb+=we[192+h];} P[142]=a; P[143]=bb; }
      else if (f==6){ float a,bb; halfsum(vbv, a,bb); P[144]=a; P[145]=bb; }
      else          { float a,bb; halfsum(vbe, a,bb); P[146]=a; P[147]=bb; }
    }
  } else {
    const int cb = b - 90;
    const int t = cb / 8, chunk = cb % 8;
    const int lT = c_lT[c_dtype[t]];
    __shared__ int scnt[32];
    if (threadIdx.x < 32) scnt[threadIdx.x] = 0;
    __syncthreads();
    const int* __restrict__ dstp = eidx + (size_t)(t*2+1)*NE;
    const int e0 = chunk*CHUNK, e1 = min(NE, e0+CHUNK);
    for (int e=e0+threadIdx.x; e<e1; e+=1024) atomicAdd(&scnt[dstp[e]>>lT], 1);
    __syncthreads();
    if (threadIdx.x < 32) gcnt8[(t*8 + chunk)*32 + threadIdx.x] = scnt[threadIdx.x];
  }
}

// ---- scan: sum chunk counts -> gcnt/gofs/gcur; init mm. 1 block. ----
__global__ void k_scan(const int* __restrict__ gcnt8, int* __restrict__ gcnt,
                       int* __restrict__ gofs, int* __restrict__ gcur,
                       unsigned* __restrict__ mm){
  const int t = threadIdx.x;
  if (t == 16){ mm[0] = 0xFFFFFFFFu; }
  else if (t == 17){ mm[1] = 0u; }
  if (t >= 15) return;
  const int b0 = c_tprefix[t], b1 = c_tprefix[t+1];
  int run = t*NE;
  for (int b=b0; b<b1; b++){
    const int tile = b - b0;
    int c0 = 0;
    #pragma unroll
    for (int c=0; c<8; c++) c0 += gcnt8[(t*8 + c)*32 + tile];
    gcnt[b] = c0;
    gofs[b] = run; gcur[b] = run;
    run += c0;
  }
}

// ---- scatter packed payload {src<<10|dl, ea f16x2} into per-dtype-sized tile buckets ----
__global__ __launch_bounds__(1024) void k_scatter(const int* __restrict__ eidx,
    const float* __restrict__ eattr,
    int* __restrict__ gcur, uint2* __restrict__ ebuf){
  const int t = blockIdx.y;
  const int lT = c_lT[c_dtype[t]];
  const int tmask = (1<<lT) - 1;
  __shared__ int lcnt[32], lbase[32];
  if (threadIdx.x < 32) lcnt[threadIdx.x] = 0;
  __syncthreads();
  const int* __restrict__ dstp = eidx + (size_t)(t*2+1)*NE;
  const int* __restrict__ srcp = eidx + (size_t)(t*2)*NE;
  const float2* __restrict__ ea2 = (const float2*)eattr + (size_t)t*NE;
  const int e0 = blockIdx.x*CHUNK, e1 = min(NE, e0+CHUNK);
  for (int e=e0+threadIdx.x; e<e1; e+=1024) atomicAdd(&lcnt[dstp[e]>>lT], 1);
  __syncthreads();
  if (threadIdx.x < 32){
    int cchk = lcnt[threadIdx.x];
    lbase[threadIdx.x] = cchk > 0 ? atomicAdd(&gcur[c_tprefix[t]+threadIdx.x], cchk) : 0;
  }
  __syncthreads();
  if (threadIdx.x < 32) lcnt[threadIdx.x] = 0;
  __syncthreads();
  for (int e=e0+threadIdx.x; e<e1; e+=1024){
    const int d = dstp[e];
    const int tile = d>>lT, dl = d & tmask;
    const int pos = lbase[tile] + atomicAdd(&lcnt[tile], 1);
    const float2 ea = ea2[e];
    __half2 h2 = __floats2half2_rn(ea.x, ea.y);
    ebuf[pos] = make_uint2(((unsigned)srcp[e]<<10) | (unsigned)dl, *(unsigned*)&h2);
  }
}

// ---- per-bucket row sort: pure permutation of the 8B payload on 432
// balanced buckets (~5-6K edges each). ----
__global__ __launch_bounds__(1024) void k_tsort(
    const uint2* __restrict__ ebuf,
    const int* __restrict__ gofs, const int* __restrict__ gcnt,
    uint2* __restrict__ erec, int* __restrict__ gs2, int* __restrict__ glen){
  const int b = blockIdx.x;
  int t = 0;
  while (b >= c_tprefix[t+1]) ++t;
  const int tile = b - c_tprefix[t];
  const int dt = c_dtype[t];
  const int N = c_N[dt];
  const int lT = c_lT[dt];
  const int nbase = tile << lT;
  const int tileN = min(1<<lT, N - nbase);
  const int tid = threadIdx.x;
  const int lane = tid & 63, wid = tid >> 6;

  __shared__ int cnt[1024];
  __shared__ int wsum[16];

  cnt[tid] = 0;
  __syncthreads();
  const int start = gofs[b], count = gcnt[b];
  for (int k=tid; k<count; k+=1024) atomicAdd(&cnt[ebuf[start+k].x & 1023u], 1);
  __syncthreads();
  const int v = cnt[tid];
  int inc = v;
  #pragma unroll
  for (int off=1; off<64; off<<=1){ int u = __shfl_up(inc, off); if (lane>=off) inc += u; }
  if (lane==63) wsum[wid] = inc;
  __syncthreads();
  if (tid==0){ int r=0; for (int k=0;k<16;k++){ int x=wsum[k]; wsum[k]=r; r+=x; } }
  __syncthreads();
  const int pref = wsum[wid] + inc - v;
  if (tid < tileN){
    gs2 [c_toff2[t] + nbase + tid] = start + pref;
    glen[c_toff2[t] + nbase + tid] = v;
  }
  cnt[tid] = pref;
  __syncthreads();
  for (int k=tid; k<count; k+=1024){
    const uint2 u2 = ebuf[start+k];
    const int dl = u2.x & 1023u;
    const int pos = start + atomicAdd(&cnt[dl], 1);
    erec[pos] = make_uint2(u2.x >> 10, u2.y);
  }
}

// ---- gather: per (type,node) walk sorted run ONCE with 1-deep software
// pipeline (next erec + next xall issued before current compute). ----
__global__ __launch_bounds__(256) void k_gather(
    const int* __restrict__ gs2, const int* __restrict__ glen,
    const uint2* __restrict__ erec,
    const float* __restrict__ xall, const float* __restrict__ par,
    const float* __restrict__ Wl, const float* __restrict__ bl,
    float* __restrict__ g, unsigned* __restrict__ mm){
  const int t = blockIdx.y;
  const int dt = c_dtype[t], st = c_stype[t];
  const int N = c_N[dt];
  if (blockIdx.x*256 >= N) return;
  __shared__ float sA[160], sB[160];
  __shared__ float wlb[192];
  __shared__ float smin[4], smax[4];
  const int tid = threadIdx.x;
  if (tid < 160){ sA[tid] = par[(size_t)t*160 + tid]; sB[tid] = par[(size_t)(15+t)*160 + tid]; }
  if (tid < 192) wlb[tid] = (tid<128)? Wl[tid] : bl[tid-128];
  __syncthreads();
  const int n = blockIdx.x*256 + tid;
  const bool valid = n < N;
  float lmin = 3.4e38f, lmax = -3.4e38f;
  if (valid){
    const float4* xdp = (const float4*)(xall + (size_t)(c_xoff[dt]+n)*8);
    float4 b0v = xdp[0], b1v = xdp[1];
    float xd[8] = {b0v.x,b0v.y,b0v.z,b0v.w,b1v.x,b1v.y,b1v.z,b1v.w};
    float r2a[8], r2b[8];
    #pragma unroll
    for (int fs=0; fs<8; fs++){
      float a = sA[72+fs], bb = sB[72+fs];
      #pragma unroll
      for (int fd=0; fd<8; fd++){ a = fmaf(xd[fd], sA[fd*8+fs], a); bb = fmaf(xd[fd], sB[fd*8+fs], bb); }
      r2a[fs]=a; r2b[fs]=bb;
    }
    float t0a=sA[137], t1a=sA[138], tba=sA[139], u0a=sA[136];
    float t0b=sB[137], t1b=sB[138], tbb=sB[139], u0b=sB[136];
    #pragma unroll
    for (int f=0;f<8;f++){
      t0a = fmaf(xd[f], sA[80+f], t0a);  t0b = fmaf(xd[f], sB[80+f], t0b);
      t1a = fmaf(xd[f], sA[88+f], t1a);  t1b = fmaf(xd[f], sB[88+f], t1b);
      tba = fmaf(xd[f], sA[96+f], tba);  tbb = fmaf(xd[f], sB[96+f], tbb);
      u0a = fmaf(xd[f], sA[64+f], u0a);  u0b = fmaf(xd[f], sB[64+f], u0b);
    }
    const float accda = u0a + tba, accdb = u0b + tbb;
    const int o = c_toff2[t];
    const int js = gs2[o+n], je = js + glen[o+n];
    float denA=0.f, n0A=0.f, n1A=0.f;
    float denB=0.f, n0B=0.f, n1B=0.f;
    if (je > js){
      uint2 rec = erec[js];
      const float4* xp0 = (const float4*)(xall + (size_t)(c_xoff[st]+(int)rec.x)*8);
      float4 xa = xp0[0], xb = xp0[1];
      for (int j=js; j<je; j++){
        // issue next iteration's loads before current compute
        const int jn = (j+1 < je) ? j+1 : j;
        const uint2 recn = erec[jn];
        const float4* xpn = (const float4*)(xall + (size_t)(c_xoff[st]+(int)recn.x)*8);
        const float4 xan = xpn[0], xbn = xpn[1];
        // compute current
        const __half2 h2 = *(const __half2*)&rec.y;
        const float eax = __low2float(h2), eay = __high2float(h2);
        float xs[8] = {xa.x,xa.y,xa.z,xa.w,xb.x,xb.y,xb.z,xb.w};
        float accA = accda, accB = accdb;
        float v0A = fmaf(eax, sA[140], fmaf(eay, sA[142], sA[144]+sA[146]));
        float v1A = fmaf(eax, sA[141], fmaf(eay, sA[143], sA[145]+sA[147]));
        float v0B = fmaf(eax, sB[140], fmaf(eay, sB[142], sB[144]+sB[146]));
        float v1B = fmaf(eax, sB[141], fmaf(eay, sB[143], sB[145]+sB[147]));
        #pragma unroll
        for (int f=0;f<8;f++){
          accA = fmaf(xs[f], r2a[f], accA);   accB = fmaf(xs[f], r2b[f], accB);
          v0A  = fmaf(xs[f], sA[104+f], v0A); v0B  = fmaf(xs[f], sB[104+f], v0B);
          v1A  = fmaf(xs[f], sA[112+f], v1A); v1B  = fmaf(xs[f], sB[112+f], v1B);
        }
        accA = fmaf(eax, t0a, fmaf(eay, t1a, accA));
        accB = fmaf(eax, t0b, fmaf(eay, t1b, accB));
        const float peA = __expf(accA * 0.08838834764831845f);
        const float peB = __expf(accB * 0.08838834764831845f);
        denA += peA; n0A = fmaf(peA, v0A, n0A); n1A = fmaf(peA, v1A, n1A);
        denB += peB; n0B = fmaf(peB, v0B, n0B); n1B = fmaf(peB, v1B, n1B);
        rec = recn; xa = xan; xb = xbn;
      }
    }
    const float invA = 1.0f/(denA + 1e-16f);
    const float invB = 1.0f/(denB + 1e-16f);
    float s0a = fmaf(n0A, invA, sA[148]), s1a = fmaf(n1A, invA, sA[149]);
    float s0b = fmaf(n0B, invB, sB[148]), s1b = fmaf(n1B, invB, sB[149]);
    #pragma unroll
    for (int f=0;f<8;f++){
      s0a = fmaf(xd[f], sA[120+f], s0a); s1a = fmaf(xd[f], sA[128+f], s1a);
      s0b = fmaf(xd[f], sB[120+f], s0b); s1b = fmaf(xd[f], sB[128+f], s1b);
    }
    const int baseA = c_aggoff[dt] + (0*c_cnt[dt] + c_slot[t])*N + n;
    const int baseB = c_aggoff[dt] + (1*c_cnt[dt] + c_slot[t])*N + n;
    ((float2*)g)[baseA] = make_float2(s0a, s1a);
    ((float2*)g)[baseB] = make_float2(s0b, s1b);
    #pragma unroll
    for (int h=0;h<64;h++){
      float za = fmaf(s0a, wlb[h], fmaf(s1a, wlb[64+h], wlb[128+h]));
      float zb = fmaf(s0b, wlb[h], fmaf(s1b, wlb[64+h], wlb[128+h]));
      lmin = fminf(lmin, fminf(za,zb)); lmax = fmaxf(lmax, fmaxf(za,zb));
    }
  }
  #pragma unroll
  for (int m=32;m>=1;m>>=1){
    lmin = fminf(lmin, __shfl_xor(lmin,m));
    lmax = fmaxf(lmax, __shfl_xor(lmax,m));
  }
  const int wv = tid>>6;
  if ((tid&63)==0){ smin[wv]=lmin; smax[wv]=lmax; }
  __syncthreads();
  if (tid==0){
    float mn = fminf(fminf(smin[0],smin[1]), fminf(smin[2],smin[3]));
    float mx = fmaxf(fmaxf(smax[0],smax[1]), fmaxf(smax[2],smax[3]));
    atomicMin(&mm[0], encf(mn));
    atomicMax(&mm[1], encf(mx));
  }
}

// ---- final: f16 MFMA matvec (layouts verified R11, absmax 0.031) ----
__global__ __launch_bounds__(256) void k_final(
    const float* __restrict__ g, const unsigned* __restrict__ mm,
    const float* __restrict__ Wl, const float* __restrict__ bl,
    const float* __restrict__ Wfc, const float* __restrict__ bfc,
    const float* __restrict__ Wl2, const float* __restrict__ bl2,
    float* __restrict__ out){
  const int gw = blockIdx.x*4 + (threadIdx.x>>6);   // global wave id, 64 rows each
  const int l  = threadIdx.x & 63;
  const int lr = l & 15, lg = l >> 4;
  int nt, wo;
  if (gw < 375)       { nt=0; wo=0; }
  else if (gw < 4125) { nt=1; wo=375; }
  else if (gw < 6000) { nt=2; wo=4125; }
  else                { nt=3; wo=6000; }
  const int R = c_aggrows[nt];
  const int r0 = (gw - wo)*64;
  const float zmin = decf(mm[0]), zmax = decf(mm[1]);
  const float rmin = 0.1f*eluf(zmin);
  const float rmax = 0.9f + 0.1f*eluf(zmax);
  const float s2 = 2.0f/(rmax - rmin + 1e-5f);
  const float cc = fmaf(-rmin, s2, -1.0f);
  float wl0v[2][8], wl1v[2][8], blv[2][8];
  #pragma unroll
  for (int kk=0; kk<2; kk++){
    const int hb = kk*32 + lg*8;
    const float4 a0 = *(const float4*)&Wl[hb],    a1 = *(const float4*)&Wl[hb+4];
    const float4 b0 = *(const float4*)&Wl[64+hb], b1 = *(const float4*)&Wl[64+hb+4];
    const float4 c0 = *(const float4*)&bl[hb],    c1 = *(const float4*)&bl[hb+4];
    wl0v[kk][0]=a0.x; wl0v[kk][1]=a0.y; wl0v[kk][2]=a0.z; wl0v[kk][3]=a0.w;
    wl0v[kk][4]=a1.x; wl0v[kk][5]=a1.y; wl0v[kk][6]=a1.z; wl0v[kk][7]=a1.w;
    wl1v[kk][0]=b0.x; wl1v[kk][1]=b0.y; wl1v[kk][2]=b0.z; wl1v[kk][3]=b0.w;
    wl1v[kk][4]=b1.x; wl1v[kk][5]=b1.y; wl1v[kk][6]=b1.z; wl1v[kk][7]=b1.w;
    blv[kk][0]=c0.x;  blv[kk][1]=c0.y;  blv[kk][2]=c0.z;  blv[kk][3]=c0.w;
    blv[kk][4]=c1.x;  blv[kk][5]=c1.y;  blv[kk][6]=c1.z;  blv[kk][7]=c1.w;
  }
  const float* __restrict__ W = Wfc + (size_t)nt*4096;
  f16x8 bfrag[2][4];
  #pragma unroll
  for (int kk=0; kk<2; kk++){
    #pragma unroll
    for (int ntl=0; ntl<4; ntl++){
      #pragma unroll
      for (int j=0; j<8; j++){
        const int h = kk*32 + lg*8 + j;
        bfrag[kk][ntl][j] = (_Float16)W[h*64 + ntl*16 + lr];
      }
    }
  }
  const float bf0 = bfc[nt*64 + lr],      bf1 = bfc[nt*64 + 16 + lr];
  const float bf2 = bfc[nt*64 + 32 + lr], bf3 = bfc[nt*64 + 48 + lr];
  const float2* __restrict__ g2p = (const float2*)g + c_aggoff[nt] + r0;
  const float wl20 = Wl2[l], wl21 = Wl2[64+l], bl2v = bl2[l];
  float* __restrict__ o1 = out + ((size_t)c_outoff[nt] + r0)*64 + l;
  float* __restrict__ o2 = o1 + (size_t)R*64;
  #pragma unroll
  for (int mt=0; mt<4; mt++){
    const float2 gv = g2p[mt*16 + lr];
    f16x8 af0, af1;
    #pragma unroll
    for (int j=0; j<8; j++){
      const float z0 = fmaf(gv.x, wl0v[0][j], fmaf(gv.y, wl1v[0][j], blv[0][j]));
      const float z1 = fmaf(gv.x, wl0v[1][j], fmaf(gv.y, wl1v[1][j], blv[1][j]));
      af0[j] = (_Float16)fmaf(elufast(z0), s2, cc);
      af1[j] = (_Float16)fmaf(elufast(z1), s2, cc);
    }
    f32x4 d0 = {0.f,0.f,0.f,0.f}, d1 = {0.f,0.f,0.f,0.f};
    f32x4 d2 = {0.f,0.f,0.f,0.f}, d3 = {0.f,0.f,0.f,0.f};
    d0 = __builtin_amdgcn_mfma_f32_16x16x32_f16(af0, bfrag[0][0], d0, 0,0,0);
    d1 = __builtin_amdgcn_mfma_f32_16x16x32_f16(af0, bfrag[0][1], d1, 0,0,0);
    d2 = __builtin_amdgcn_mfma_f32_16x16x32_f16(af0, bfrag[0][2], d2, 0,0,0);
    d3 = __builtin_amdgcn_mfma_f32_16x16x32_f16(af0, bfrag[0][3], d3, 0,0,0);
    d0 = __builtin_amdgcn_mfma_f32_16x16x32_f16(af1, bfrag[1][0], d0, 0,0,0);
    d1 = __builtin_amdgcn_mfma_f32_16x16x32_f16(af1, bfrag[1][1], d1, 0,0,0);
    d2 = __builtin_amdgcn_mfma_f32_16x16x32_f16(af1, bfrag[1][2], d2, 0,0,0);
    d3 = __builtin_amdgcn_mfma_f32_16x16x32_f16(af1, bfrag[1][3], d3, 0,0,0);
    float ph0[4], ph1[4];
    #pragma unroll
    for (int reg=0; reg<4; reg++){
      float p0 = elufast(d0[reg] + bf0) + elufast(d1[reg] + bf1);
      float p1 = elufast(d2[reg] + bf2) + elufast(d3[reg] + bf3);
      p0 += __shfl_xor(p0,1); p0 += __shfl_xor(p0,2); p0 += __shfl_xor(p0,4); p0 += __shfl_xor(p0,8);
      p1 += __shfl_xor(p1,1); p1 += __shfl_xor(p1,2); p1 += __shfl_xor(p1,4); p1 += __shfl_xor(p1,8);
      ph0[reg] = p0; ph1[reg] = p1;
    }
    #pragma unroll
    for (int rt=0; rt<16; rt++){
      const int r = mt*16 + rt;
      const float h0r = RL(ph0[rt&3], (rt>>2)<<4);
      const float h1r = RL(ph1[rt&3], (rt>>2)<<4);
      const float f = elufast(fmaf(h0r, wl20, fmaf(h1r, wl21, bl2v)));
      o1[(size_t)r*64] = f;
      o2[(size_t)r*64] = f;
    }
  }
}

extern "C" void kernel_launch(void* const* d_in, const int* in_sizes, int n_in,
                              void* d_out, int out_size, void* d_ws, size_t ws_size,
                              hipStream_t stream) {
  const float* xSB = (const float*)d_in[0];
  const float* cSB = (const float*)d_in[1];
  const float* xPQ = (const float*)d_in[2];
  const float* cPQ = (const float*)d_in[3];
  const float* xPV = (const float*)d_in[4];
  const float* cPV = (const float*)d_in[5];
  const float* xNB = (const float*)d_in[6];
  const float* cNB = (const float*)d_in[7];
  const int*   eidx = (const int*)d_in[8];
  const float* eattr= (const float*)d_in[9];
  const float* Wq = (const float*)d_in[10];
  const float* bq = (const float*)d_in[11];
  const float* Wk = (const float*)d_in[12];
  const float* bk = (const float*)d_in[13];
  const float* Wv = (const float*)d_in[14];
  const float* bv = (const float*)d_in[15];
  const float* We = (const float*)d_in[16];
  const float* be = (const float*)d_in[17];
  const float* Ws = (const float*)d_in[18];
  const float* bs = (const float*)d_in[19];
  const float* Wl = (const float*)d_in[20];
  const float* bl = (const float*)d_in[21];
  const float* Wfc= (const float*)d_in[22];
  const float* bfc= (const float*)d_in[23];
  const float* Wl2= (const float*)d_in[24];
  const float* bl2= (const float*)d_in[25];

  float* ws    = (float*)d_ws;
  float* xall  = ws + 0;                    // 488000 f
  float* par   = ws + 488000;               // 4800 f
  int* gs2     = (int*)(ws + 492800);       // 240015 i
  int* glen    = (int*)(ws + 732815);       // 240015 i
  int* gcnt    = (int*)(ws + 972830);       // 432 i
  int* gofs    = (int*)(ws + 973262);       // 432 i
  int* gcur    = (int*)(ws + 973694);       // 432 i
  unsigned* mm = (unsigned*)(ws + 974126);  // 2
  int* gcnt8   = (int*)(ws + 974128);       // 3840 i (15*8*32, written unconditionally)
  uint2* ebuf  = (uint2*)(ws + 977968);     // 2250000 uint2 (even offset)
  uint2* erec  = (uint2*)(ws + 5477968);    // 2250000 uint2 (even offset)
  float* g     = ws + 9977968;              // 960000 f
  // end: 10937968 floats ~= 43.8 MB

  k_front<<<210, 1024, 0, stream>>>(xSB,cSB,xPQ,cPQ,xPV,cPV,xNB,cNB, eidx,
                                    Wq,bq,Wk,bk,Wv,bv,We,be,Ws,bs,
                                    xall, par, gcnt8);
  k_scan<<<1, 64, 0, stream>>>(gcnt8, gcnt, gofs, gcur, mm);
  dim3 gb(8, 15);
  k_scatter<<<gb, 1024, 0, stream>>>(eidx, eattr, gcur, ebuf);
  k_tsort<<<432, 1024, 0, stream>>>(ebuf, gofs, gcnt, erec, gs2, glen);
  dim3 gg(118, 15);
  k_gather<<<gg, 256, 0, stream>>>(gs2, glen, erec, xall, par, Wl, bl, g, mm);
  k_final<<<1875, 256, 0, stream>>>(g, mm, Wl, bl, Wfc, bfc, Wl2, bl2, (float*)d_out);
}